// Round 1
// baseline (1449.545 us; speedup 1.0000x reference)
//
#include <hip/hip_runtime.h>
#include <hip/hip_cooperative_groups.h>
#include <math.h>

namespace cg = cooperative_groups;

#define NSNPS  500000
#define NGENES 20000
#define NNODES 600000
#define NEDGES 320000
#define BB     16
#define NFILT  8
#define NBLK2  5000   // gin virtual-grid = (NGENES/16)*4

// rsqrt(1 + 1e-5)
#define BN_SCALE 0.99999500003749968f

typedef unsigned short u16;

__device__ __forceinline__ float gelu_erf(float x) {
    return 0.5f * x * (1.0f + erff(x * 0.70710678118654752f));
}
__device__ __forceinline__ float sigmoidf_(float x) {
    return 1.0f / (1.0f + expf(-x));
}
// fp32 -> bf16 round-to-nearest-even
__device__ __forceinline__ u16 f2bf(float x) {
    unsigned u = __float_as_uint(x);
    u += 0x7fffu + ((u >> 16) & 1u);
    return (u16)(u >> 16);
}
__device__ __forceinline__ float bf1(u16 v)      { return __uint_as_float(((unsigned)v) << 16); }
__device__ __forceinline__ float bflo(unsigned v){ return __uint_as_float(v << 16); }
__device__ __forceinline__ float bfhi(unsigned v){ return __uint_as_float(v & 0xffff0000u); }
__device__ __forceinline__ unsigned pack2(float a, float b) {
    return (unsigned)f2bf(a) | ((unsigned)f2bf(b) << 16);
}

// ===========================================================================
// ============ FALLBACK PATH: original 9-kernel pipeline (verbatim) =========
// ===========================================================================
#define PREP_NA 1954   // ceil(NSNPS/256)
#define PREP_NB 1954
#define PREP_NC 79     // ceil((NGENES+1)/256)
__global__ __launch_bounds__(256) void k_prep(const float* __restrict__ snp,
                                              const float* __restrict__ filters,
                                              const int* __restrict__ gene_of_node,
                                              u16* __restrict__ snpT,
                                              u16* __restrict__ filtT,
                                              float* __restrict__ out_filt,
                                              int* __restrict__ node_off,
                                              int* __restrict__ deg) {
    int bid = blockIdx.x;
    int t = threadIdx.x;
    if (bid < PREP_NA) {
        int n = bid * 256 + t;
        if (n < NSNPS) {
            float f0 = filters[0 * NSNPS + n], f1 = filters[1 * NSNPS + n];
            float f2 = filters[2 * NSNPS + n], f3 = filters[3 * NSNPS + n];
            float f4 = filters[4 * NSNPS + n], f5 = filters[5 * NSNPS + n];
            float f6 = filters[6 * NSNPS + n], f7 = filters[7 * NSNPS + n];
            uint4 p;
            p.x = pack2(f0, f1); p.y = pack2(f2, f3);
            p.z = pack2(f4, f5); p.w = pack2(f6, f7);
            *(uint4*)(filtT + (size_t)n * 8) = p;
            out_filt[0 * NSNPS + n] = f0; out_filt[1 * NSNPS + n] = f1;
            out_filt[2 * NSNPS + n] = f2; out_filt[3 * NSNPS + n] = f3;
            out_filt[4 * NSNPS + n] = f4; out_filt[5 * NSNPS + n] = f5;
            out_filt[6 * NSNPS + n] = f6; out_filt[7 * NSNPS + n] = f7;
        }
    } else if (bid < PREP_NA + PREP_NB) {
        int n = (bid - PREP_NA) * 256 + t;
        if (n < NSNPS) {
            uint4 p0, p1;
            p0.x = pack2(snp[0 * (size_t)NSNPS + n],  snp[1 * (size_t)NSNPS + n]);
            p0.y = pack2(snp[2 * (size_t)NSNPS + n],  snp[3 * (size_t)NSNPS + n]);
            p0.z = pack2(snp[4 * (size_t)NSNPS + n],  snp[5 * (size_t)NSNPS + n]);
            p0.w = pack2(snp[6 * (size_t)NSNPS + n],  snp[7 * (size_t)NSNPS + n]);
            p1.x = pack2(snp[8 * (size_t)NSNPS + n],  snp[9 * (size_t)NSNPS + n]);
            p1.y = pack2(snp[10 * (size_t)NSNPS + n], snp[11 * (size_t)NSNPS + n]);
            p1.z = pack2(snp[12 * (size_t)NSNPS + n], snp[13 * (size_t)NSNPS + n]);
            p1.w = pack2(snp[14 * (size_t)NSNPS + n], snp[15 * (size_t)NSNPS + n]);
            uint4* dst = (uint4*)(snpT + (size_t)n * 16);
            dst[0] = p0; dst[1] = p1;
        }
    } else {
        int g = (bid - PREP_NA - PREP_NB) * 256 + t;
        if (g < NGENES) deg[g] = 0;
        if (g <= NGENES) {
            int lo = 0, hi = NNODES;
            while (lo < hi) {
                int mid = (lo + hi) >> 1;
                if (gene_of_node[mid] < g) lo = mid + 1; else hi = mid;
            }
            node_off[g] = lo;
        }
    }
}

__global__ __launch_bounds__(256) void k_deg(const int* __restrict__ edge_dst,
                                             int* __restrict__ deg) {
    int e = blockIdx.x * 256 + threadIdx.x;
    if (e >= NEDGES) return;
    atomicAdd(&deg[edge_dst[e]], 1);
}

__global__ __launch_bounds__(1024) void k_scan(const int* __restrict__ deg,
                                               int* __restrict__ csr_off,
                                               int* __restrict__ cursor) {
    __shared__ int sums[1024];
    int t = threadIdx.x;
    const int CH = (NGENES + 1023) / 1024;   // 20
    int base = t * CH;
    int s = 0;
    for (int i = 0; i < CH; i++) {
        int idx = base + i;
        if (idx < NGENES) s += deg[idx];
    }
    sums[t] = s;
    __syncthreads();
    for (int off = 1; off < 1024; off <<= 1) {
        int v = (t >= off) ? sums[t - off] : 0;
        __syncthreads();
        sums[t] += v;
        __syncthreads();
    }
    int run = (t == 0) ? 0 : sums[t - 1];
    for (int i = 0; i < CH; i++) {
        int idx = base + i;
        if (idx < NGENES) {
            csr_off[idx] = run;
            cursor[idx]  = run;
            run += deg[idx];
        }
    }
    if (t == 1023) csr_off[NGENES] = sums[1023];
}

__global__ __launch_bounds__(256) void k_scatter(const int* __restrict__ edge_src,
                                                 const int* __restrict__ edge_dst,
                                                 int* __restrict__ cursor,
                                                 int* __restrict__ csr_src) {
    int e = blockIdx.x * 256 + threadIdx.x;
    if (e >= NEDGES) return;
    int p = atomicAdd(&cursor[edge_dst[e]], 1);
    csr_src[p] = edge_src[e];
}

__global__ __launch_bounds__(256) void k_snp2gene(const u16* __restrict__ snpT,
                                                  const int* __restrict__ snp_ids,
                                                  const int* __restrict__ node_off,
                                                  const u16* __restrict__ filtT,
                                                  u16* __restrict__ h_bf) {
    __shared__ float sZ[4][128];
    int t = threadIdx.x;
    int wave = t >> 6, lane = t & 63;
    int g = blockIdx.x;
    int sub = (wave << 2) + (lane >> 4);
    int b = lane & 15;
    int s = node_off[g], e = node_off[g + 1];

    float acc[8];
    #pragma unroll
    for (int f = 0; f < 8; f++) acc[f] = 0.0f;

    int i = s + sub;
    for (; i + 16 < e; i += 32) {
        int id0 = snp_ids[i];
        int id1 = snp_ids[i + 16];
        float v0 = bf1(snpT[(size_t)id0 * 16 + b]);
        float v1 = bf1(snpT[(size_t)id1 * 16 + b]);
        uint4 F0 = *(const uint4*)(filtT + (size_t)id0 * 8);
        uint4 F1 = *(const uint4*)(filtT + (size_t)id1 * 8);
        acc[0] += v0 * bflo(F0.x) + v1 * bflo(F1.x);
        acc[1] += v0 * bfhi(F0.x) + v1 * bfhi(F1.x);
        acc[2] += v0 * bflo(F0.y) + v1 * bflo(F1.y);
        acc[3] += v0 * bfhi(F0.y) + v1 * bfhi(F1.y);
        acc[4] += v0 * bflo(F0.z) + v1 * bflo(F1.z);
        acc[5] += v0 * bfhi(F0.z) + v1 * bfhi(F1.z);
        acc[6] += v0 * bflo(F0.w) + v1 * bflo(F1.w);
        acc[7] += v0 * bfhi(F0.w) + v1 * bfhi(F1.w);
    }
    if (i < e) {
        int id0 = snp_ids[i];
        float v0 = bf1(snpT[(size_t)id0 * 16 + b]);
        uint4 F0 = *(const uint4*)(filtT + (size_t)id0 * 8);
        acc[0] += v0 * bflo(F0.x); acc[1] += v0 * bfhi(F0.x);
        acc[2] += v0 * bflo(F0.y); acc[3] += v0 * bfhi(F0.y);
        acc[4] += v0 * bflo(F0.z); acc[5] += v0 * bfhi(F0.z);
        acc[6] += v0 * bflo(F0.w); acc[7] += v0 * bfhi(F0.w);
    }
    #pragma unroll
    for (int f = 0; f < 8; f++) {
        acc[f] += __shfl_xor(acc[f], 16, 64);
        acc[f] += __shfl_xor(acc[f], 32, 64);
    }
    if (lane < 16) {
        float* dst = &sZ[wave][lane * 8];
        *(float4*)(dst)     = make_float4(acc[0], acc[1], acc[2], acc[3]);
        *(float4*)(dst + 4) = make_float4(acc[4], acc[5], acc[6], acc[7]);
    }
    __syncthreads();
    if (t < 128) {
        float val = sZ[0][t] + sZ[1][t] + sZ[2][t] + sZ[3][t];
        h_bf[(size_t)g * 128 + t] = f2bf(val);
    }
}

__global__ __launch_bounds__(256) void k_gin1(const u16* __restrict__ hin,
                                              u16* __restrict__ hout,
                                              const int* __restrict__ csr_off,
                                              const int* __restrict__ csr_src,
                                              const float* __restrict__ eps_l,
                                              const float* __restrict__ W1,
                                              const float* __restrict__ b1,
                                              const float* __restrict__ g1,
                                              const float* __restrict__ bt1,
                                              const float* __restrict__ W2,
                                              const float* __restrict__ b2,
                                              const float* __restrict__ g2,
                                              const float* __restrict__ bt2) {
    __shared__ float sW1[128], sb1[16], sg1[16], sbt1[16];
    __shared__ float sW2[128], sb2[8], sg2[8], sbt2[8];
    int t = threadIdx.x;
    if (t < 128) { sW1[t] = W1[t]; sW2[t] = W2[t]; }
    if (t < 16)  { sb1[t] = b1[t]; sg1[t] = g1[t]; sbt1[t] = bt1[t]; }
    if (t < 8)   { sb2[t] = b2[t]; sg2[t] = g2[t]; sbt2[t] = bt2[t]; }

    int chunk = blockIdx.x & 3;
    int g = (blockIdx.x >> 2) * 16 + (t >> 4);
    int u = t & 15;
    int half = u >> 3;
    int colpos = u & 7;
    int fh = colpos & 1;
    int jgroup = half * 2 + fh;
    int col = chunk * 32 + colpos * 4;
    const u16* __restrict__ hc = hin + col;
    float epsv = 1.0f + eps_l[0];

    float a0, a1, a2, a3;
    if (half == 0) {
        uint2 su = *(const uint2*)(hc + (size_t)g * 128);
        a0 = bflo(su.x) * epsv; a1 = bfhi(su.x) * epsv;
        a2 = bflo(su.y) * epsv; a3 = bfhi(su.y) * epsv;
    } else {
        a0 = a1 = a2 = a3 = 0.0f;
    }

    int s = csr_off[g], e = csr_off[g + 1];
    int k = s + half;
    for (; k + 14 < e; k += 16) {
        int i0 = csr_src[k],      i1 = csr_src[k + 2];
        int i2 = csr_src[k + 4],  i3 = csr_src[k + 6];
        int i4 = csr_src[k + 8],  i5 = csr_src[k + 10];
        int i6 = csr_src[k + 12], i7 = csr_src[k + 14];
        uint2 v0 = *(const uint2*)(hc + (size_t)i0 * 128);
        uint2 v1 = *(const uint2*)(hc + (size_t)i1 * 128);
        uint2 v2 = *(const uint2*)(hc + (size_t)i2 * 128);
        uint2 v3 = *(const uint2*)(hc + (size_t)i3 * 128);
        uint2 v4 = *(const uint2*)(hc + (size_t)i4 * 128);
        uint2 v5 = *(const uint2*)(hc + (size_t)i5 * 128);
        uint2 v6 = *(const uint2*)(hc + (size_t)i6 * 128);
        uint2 v7 = *(const uint2*)(hc + (size_t)i7 * 128);
        a0 += ((bflo(v0.x) + bflo(v1.x)) + (bflo(v2.x) + bflo(v3.x)))
            + ((bflo(v4.x) + bflo(v5.x)) + (bflo(v6.x) + bflo(v7.x)));
        a1 += ((bfhi(v0.x) + bfhi(v1.x)) + (bfhi(v2.x) + bfhi(v3.x)))
            + ((bfhi(v4.x) + bfhi(v5.x)) + (bfhi(v6.x) + bfhi(v7.x)));
        a2 += ((bflo(v0.y) + bflo(v1.y)) + (bflo(v2.y) + bflo(v3.y)))
            + ((bflo(v4.y) + bflo(v5.y)) + (bflo(v6.y) + bflo(v7.y)));
        a3 += ((bfhi(v0.y) + bfhi(v1.y)) + (bfhi(v2.y) + bfhi(v3.y)))
            + ((bfhi(v4.y) + bfhi(v5.y)) + (bfhi(v6.y) + bfhi(v7.y)));
    }
    for (; k < e; k += 2) {
        int i0 = csr_src[k];
        uint2 v0 = *(const uint2*)(hc + (size_t)i0 * 128);
        a0 += bflo(v0.x); a1 += bfhi(v0.x);
        a2 += bflo(v0.y); a3 += bfhi(v0.y);
    }
    __syncthreads();

    a0 += __shfl_xor(a0, 8, 64);
    a1 += __shfl_xor(a1, 8, 64);
    a2 += __shfl_xor(a2, 8, 64);
    a3 += __shfl_xor(a3, 8, 64);
    float p0 = __shfl_xor(a0, 1, 64);
    float p1 = __shfl_xor(a1, 1, 64);
    float p2 = __shfl_xor(a2, 1, 64);
    float p3 = __shfl_xor(a3, 1, 64);
    float z[8];
    z[fh * 4 + 0] = a0; z[fh * 4 + 1] = a1; z[fh * 4 + 2] = a2; z[fh * 4 + 3] = a3;
    z[(1 - fh) * 4 + 0] = p0; z[(1 - fh) * 4 + 1] = p1;
    z[(1 - fh) * 4 + 2] = p2; z[(1 - fh) * 4 + 3] = p3;

    float op[8];
    #pragma unroll
    for (int f = 0; f < 8; f++) op[f] = (jgroup == 0) ? sb2[f] : 0.0f;
    #pragma unroll
    for (int jj = 0; jj < 4; jj++) {
        int j = jgroup * 4 + jj;
        float s1 = sb1[j];
        #pragma unroll
        for (int i2 = 0; i2 < 8; i2++) s1 += z[i2] * sW1[i2 * 16 + j];
        s1 = s1 * BN_SCALE * sg1[j] + sbt1[j];
        s1 = gelu_erf(s1);
        #pragma unroll
        for (int f = 0; f < 8; f++) op[f] += s1 * sW2[j * 8 + f];
    }
    float r[4];
    #pragma unroll
    for (int fi = 0; fi < 4; fi++) {
        int f = fh * 4 + fi;
        float x = op[f] + __shfl_xor(op[f], 1, 64);
        x += __shfl_xor(x, 8, 64);
        r[fi] = gelu_erf(x * BN_SCALE * sg2[f] + sbt2[f]);
    }
    if (half == 0) {
        uint2 ou;
        ou.x = pack2(r[0], r[1]); ou.y = pack2(r[2], r[3]);
        *(uint2*)(hout + (size_t)g * 128 + col) = ou;
    }
}

__global__ __launch_bounds__(256) void k_gin2(const u16* __restrict__ hin,
                                              const int* __restrict__ csr_off,
                                              const int* __restrict__ csr_src,
                                              const float* __restrict__ eps_l,
                                              const float* __restrict__ W1,
                                              const float* __restrict__ b1,
                                              const float* __restrict__ g1,
                                              const float* __restrict__ bt1,
                                              const float* __restrict__ W2,
                                              const float* __restrict__ b2,
                                              const float* __restrict__ g2,
                                              const float* __restrict__ bt2,
                                              const float* __restrict__ Wk,
                                              const float* __restrict__ bk,
                                              const float* __restrict__ Wq,
                                              const float* __restrict__ Wv,
                                              const float* __restrict__ bv,
                                              float* __restrict__ w_out,
                                              float* __restrict__ partial) {
    __shared__ float sW1[128], sb1[16], sg1[16], sbt1[16];
    __shared__ float sW2[128], sb2[8], sg2[8], sbt2[8];
    __shared__ float sWk[64], sWv[64], sbk[8], sbv[8], sWq[8];
    __shared__ float sRed[4][4][8];
    int t = threadIdx.x;
    if (t < 128) { sW1[t] = W1[t]; sW2[t] = W2[t]; }
    if (t < 64)  { sWk[t] = Wk[t]; sWv[t] = Wv[t]; }
    if (t < 16)  { sb1[t] = b1[t]; sg1[t] = g1[t]; sbt1[t] = bt1[t]; }
    if (t < 8)   { sb2[t] = b2[t]; sg2[t] = g2[t]; sbt2[t] = bt2[t];
                   sbk[t] = bk[t]; sbv[t] = bv[t]; sWq[t] = Wq[t]; }

    int chunk = blockIdx.x & 3;
    int g = (blockIdx.x >> 2) * 16 + (t >> 4);
    int u = t & 15;
    int half = u >> 3;
    int colpos = u & 7;
    int fh = colpos & 1;
    int jgroup = half * 2 + fh;
    int b = chunk * 4 + (colpos >> 1);
    int col = chunk * 32 + colpos * 4;
    const u16* __restrict__ hc = hin + col;
    float epsv = 1.0f + eps_l[0];

    float a0, a1, a2, a3;
    if (half == 0) {
        uint2 su = *(const uint2*)(hc + (size_t)g * 128);
        a0 = bflo(su.x) * epsv; a1 = bfhi(su.x) * epsv;
        a2 = bflo(su.y) * epsv; a3 = bfhi(su.y) * epsv;
    } else {
        a0 = a1 = a2 = a3 = 0.0f;
    }

    int s = csr_off[g], e = csr_off[g + 1];
    int k = s + half;
    for (; k + 14 < e; k += 16) {
        int i0 = csr_src[k],      i1 = csr_src[k + 2];
        int i2 = csr_src[k + 4],  i3 = csr_src[k + 6];
        int i4 = csr_src[k + 8],  i5 = csr_src[k + 10];
        int i6 = csr_src[k + 12], i7 = csr_src[k + 14];
        uint2 v0 = *(const uint2*)(hc + (size_t)i0 * 128);
        uint2 v1 = *(const uint2*)(hc + (size_t)i1 * 128);
        uint2 v2 = *(const uint2*)(hc + (size_t)i2 * 128);
        uint2 v3 = *(const uint2*)(hc + (size_t)i3 * 128);
        uint2 v4 = *(const uint2*)(hc + (size_t)i4 * 128);
        uint2 v5 = *(const uint2*)(hc + (size_t)i5 * 128);
        uint2 v6 = *(const uint2*)(hc + (size_t)i6 * 128);
        uint2 v7 = *(const uint2*)(hc + (size_t)i7 * 128);
        a0 += ((bflo(v0.x) + bflo(v1.x)) + (bflo(v2.x) + bflo(v3.x)))
            + ((bflo(v4.x) + bflo(v5.x)) + (bflo(v6.x) + bflo(v7.x)));
        a1 += ((bfhi(v0.x) + bfhi(v1.x)) + (bfhi(v2.x) + bfhi(v3.x)))
            + ((bfhi(v4.x) + bfhi(v5.x)) + (bfhi(v6.x) + bfhi(v7.x)));
        a2 += ((bflo(v0.y) + bflo(v1.y)) + (bflo(v2.y) + bflo(v3.y)))
            + ((bflo(v4.y) + bflo(v5.y)) + (bflo(v6.y) + bflo(v7.y)));
        a3 += ((bfhi(v0.y) + bfhi(v1.y)) + (bfhi(v2.y) + bfhi(v3.y)))
            + ((bfhi(v4.y) + bfhi(v5.y)) + (bfhi(v6.y) + bfhi(v7.y)));
    }
    for (; k < e; k += 2) {
        int i0 = csr_src[k];
        uint2 v0 = *(const uint2*)(hc + (size_t)i0 * 128);
        a0 += bflo(v0.x); a1 += bfhi(v0.x);
        a2 += bflo(v0.y); a3 += bfhi(v0.y);
    }
    __syncthreads();

    a0 += __shfl_xor(a0, 8, 64);
    a1 += __shfl_xor(a1, 8, 64);
    a2 += __shfl_xor(a2, 8, 64);
    a3 += __shfl_xor(a3, 8, 64);
    float p0 = __shfl_xor(a0, 1, 64);
    float p1 = __shfl_xor(a1, 1, 64);
    float p2 = __shfl_xor(a2, 1, 64);
    float p3 = __shfl_xor(a3, 1, 64);
    float z[8];
    z[fh * 4 + 0] = a0; z[fh * 4 + 1] = a1; z[fh * 4 + 2] = a2; z[fh * 4 + 3] = a3;
    z[(1 - fh) * 4 + 0] = p0; z[(1 - fh) * 4 + 1] = p1;
    z[(1 - fh) * 4 + 2] = p2; z[(1 - fh) * 4 + 3] = p3;

    float op[8];
    #pragma unroll
    for (int f = 0; f < 8; f++) op[f] = (jgroup == 0) ? sb2[f] : 0.0f;
    #pragma unroll
    for (int jj = 0; jj < 4; jj++) {
        int j = jgroup * 4 + jj;
        float s1 = sb1[j];
        #pragma unroll
        for (int i2 = 0; i2 < 8; i2++) s1 += z[i2] * sW1[i2 * 16 + j];
        s1 = s1 * BN_SCALE * sg1[j] + sbt1[j];
        s1 = gelu_erf(s1);
        #pragma unroll
        for (int f = 0; f < 8; f++) op[f] += s1 * sW2[j * 8 + f];
    }
    float hvh[4];
    #pragma unroll
    for (int fi = 0; fi < 4; fi++) {
        int f = fh * 4 + fi;
        float x = op[f] + __shfl_xor(op[f], 1, 64);
        x += __shfl_xor(x, 8, 64);
        hvh[fi] = gelu_erf(x * BN_SCALE * sg2[f] + sbt2[f]);
    }
    float hv[8];
    #pragma unroll
    for (int fi = 0; fi < 4; fi++) {
        hv[fh * 4 + fi] = hvh[fi];
        hv[(1 - fh) * 4 + fi] = __shfl_xor(hvh[fi], 1, 64);
    }

    float qp = 0.0f;
    #pragma unroll
    for (int jj = 0; jj < 2; jj++) {
        int j = jgroup * 2 + jj;
        float key = sbk[j];
        #pragma unroll
        for (int i2 = 0; i2 < 8; i2++) key += hv[i2] * sWk[i2 * 8 + j];
        qp += key * sWq[j];
    }
    float q = qp + __shfl_xor(qp, 1, 64);
    q += __shfl_xor(q, 8, 64);
    float w = sigmoidf_(q);
    if (fh == 0 && half == 0) w_out[(size_t)b * NGENES + g] = w;

    float contrib[4];
    #pragma unroll
    for (int fi = 0; fi < 4; fi++) {
        int f = fh * 4 + fi;
        float v = sbv[f];
        #pragma unroll
        for (int i2 = 0; i2 < 8; i2++) v += hv[i2] * sWv[i2 * 8 + f];
        contrib[fi] = (half == 0) ? v * w : 0.0f;
    }
    #pragma unroll
    for (int fi = 0; fi < 4; fi++) {
        contrib[fi] += __shfl_xor(contrib[fi], 8, 64);
        contrib[fi] += __shfl_xor(contrib[fi], 16, 64);
        contrib[fi] += __shfl_xor(contrib[fi], 32, 64);
    }
    int wave = t >> 6, lane = t & 63;
    if (lane < 8) {
        #pragma unroll
        for (int fi = 0; fi < 4; fi++)
            sRed[wave][lane >> 1][(lane & 1) * 4 + fi] = contrib[fi];
    }
    __syncthreads();
    if (t < 32) {
        int bl = t >> 3, f = t & 7;
        float sm = sRed[0][bl][f] + sRed[1][bl][f] + sRed[2][bl][f] + sRed[3][bl][f];
        partial[(size_t)blockIdx.x * 32 + bl * 8 + f] = sm;
    }
}

__global__ __launch_bounds__(64) void k_reduce(const float* __restrict__ partial,
                                               float* __restrict__ g_h) {
    int bf = blockIdx.x;
    int b = bf >> 3, f = bf & 7;
    int c = b >> 2, bl = b & 3;
    int ln = threadIdx.x;
    float s = 0.0f;
    for (int j = ln; j < NBLK2 / 4; j += 64)
        s += partial[(size_t)(c + 4 * j) * 32 + bl * 8 + f];
    #pragma unroll
    for (int m = 1; m < 64; m <<= 1) s += __shfl_xor(s, m, 64);
    if (ln == 0) g_h[bf] = s;
}

__global__ __launch_bounds__(1024) void k_head(const float* __restrict__ g_h,
                                               const float* __restrict__ Wp1, const float* __restrict__ bp1,
                                               const float* __restrict__ gp1, const float* __restrict__ btp1,
                                               const float* __restrict__ Wp2, const float* __restrict__ bp2,
                                               const float* __restrict__ gp2, const float* __restrict__ btp2,
                                               const float* __restrict__ Wp3, const float* __restrict__ bp3,
                                               float* __restrict__ preds) {
    __shared__ float sgh[128];
    __shared__ float z1[16 * 64];
    __shared__ float z2[16 * 16];
    int t = threadIdx.x;
    if (t < 128) sgh[t] = g_h[t];
    __syncthreads();
    {
        int b = t >> 6, j = t & 63;
        float s = bp1[j];
        #pragma unroll
        for (int k = 0; k < 8; k++) s += sgh[b * 8 + k] * Wp1[k * 64 + j];
        s = s * BN_SCALE * gp1[j] + btp1[j];
        z1[b * 64 + j] = gelu_erf(s);
    }
    __syncthreads();
    if (t < 256) {
        int b = t >> 4, j = t & 15;
        float s = bp2[j];
        for (int k = 0; k < 64; k++) s += z1[b * 64 + k] * Wp2[k * 16 + j];
        s = s * BN_SCALE * gp2[j] + btp2[j];
        z2[b * 16 + j] = gelu_erf(s);
    }
    __syncthreads();
    if (t < 16) {
        float s = bp3[0];
        #pragma unroll
        for (int k = 0; k < 16; k++) s += z2[t * 16 + k] * Wp3[k];
        preds[t] = s;
    }
}

// ===========================================================================
// ===================== PRIMARY PATH: one cooperative kernel ================
// ===========================================================================
// Virtual-block counts per phase
#define P0A   1954      // ceil(NSNPS/256): fused snpT+filtT 64B row + fp32 filt copy
#define P0B   79        // ceil((NGENES+1)/256): node_off binsearch + deg zero
#define PEDGE 1250      // ceil(NEDGES/256)
#define NCHUNK 79       // ceil(NGENES/256) scan chunks
#define GRID_MEGA 1024  // 4 blocks/CU x 256 CUs, guaranteed by __launch_bounds__(256,4)

struct MegaParams {
    const float *snp, *filters, *eps;
    const float *W1, *b1, *g1, *bt1, *W2, *b2, *g2, *bt2;
    const float *Wk, *bk, *Wq, *Wv, *bv;
    const float *Wp1, *bp1, *gp1, *btp1, *Wp2, *bp2, *gp2, *btp2, *Wp3, *bp3;
    const int *snp_ids, *gene_of_node, *edge_src, *edge_dst;
    float *out_preds, *out_filt, *out_w;
    u16 *nodeRow, *h0, *h1;
    int *node_off, *deg, *csr_off, *cursor, *chunkTot, *csr_src;
    float *partial, *g_h;
};

// One GIN layer body for virtual block blk (verbatim math from k_gin1/k_gin2).
template<bool READOUT>
__device__ __forceinline__ void gin_body(
    int blk, int t,
    const u16* __restrict__ hin, u16* __restrict__ hout,
    const int* __restrict__ csr_off, const int* __restrict__ csr_src,
    float epsv,
    const float* __restrict__ sW1, const float* __restrict__ sb1,
    const float* __restrict__ sg1, const float* __restrict__ sbt1,
    const float* __restrict__ sW2, const float* __restrict__ sb2,
    const float* __restrict__ sg2, const float* __restrict__ sbt2,
    const float* __restrict__ sWk, const float* __restrict__ sbk,
    const float* __restrict__ sWq, const float* __restrict__ sWv,
    const float* __restrict__ sbv,
    float* __restrict__ sRedRaw,
    float* __restrict__ w_out, float* __restrict__ partial)
{
    int chunk = blk & 3;
    int g = (blk >> 2) * 16 + (t >> 4);
    int u = t & 15;
    int half = u >> 3;
    int colpos = u & 7;
    int fh = colpos & 1;
    int jgroup = half * 2 + fh;
    int col = chunk * 32 + colpos * 4;
    const u16* __restrict__ hc = hin + col;

    float a0, a1, a2, a3;
    if (half == 0) {
        uint2 su = *(const uint2*)(hc + (size_t)g * 128);
        a0 = bflo(su.x) * epsv; a1 = bfhi(su.x) * epsv;
        a2 = bflo(su.y) * epsv; a3 = bfhi(su.y) * epsv;
    } else {
        a0 = a1 = a2 = a3 = 0.0f;
    }

    int s = csr_off[g], e = csr_off[g + 1];
    int k = s + half;
    for (; k + 14 < e; k += 16) {
        int i0 = csr_src[k],      i1 = csr_src[k + 2];
        int i2 = csr_src[k + 4],  i3 = csr_src[k + 6];
        int i4 = csr_src[k + 8],  i5 = csr_src[k + 10];
        int i6 = csr_src[k + 12], i7 = csr_src[k + 14];
        uint2 v0 = *(const uint2*)(hc + (size_t)i0 * 128);
        uint2 v1 = *(const uint2*)(hc + (size_t)i1 * 128);
        uint2 v2 = *(const uint2*)(hc + (size_t)i2 * 128);
        uint2 v3 = *(const uint2*)(hc + (size_t)i3 * 128);
        uint2 v4 = *(const uint2*)(hc + (size_t)i4 * 128);
        uint2 v5 = *(const uint2*)(hc + (size_t)i5 * 128);
        uint2 v6 = *(const uint2*)(hc + (size_t)i6 * 128);
        uint2 v7 = *(const uint2*)(hc + (size_t)i7 * 128);
        a0 += ((bflo(v0.x) + bflo(v1.x)) + (bflo(v2.x) + bflo(v3.x)))
            + ((bflo(v4.x) + bflo(v5.x)) + (bflo(v6.x) + bflo(v7.x)));
        a1 += ((bfhi(v0.x) + bfhi(v1.x)) + (bfhi(v2.x) + bfhi(v3.x)))
            + ((bfhi(v4.x) + bfhi(v5.x)) + (bfhi(v6.x) + bfhi(v7.x)));
        a2 += ((bflo(v0.y) + bflo(v1.y)) + (bflo(v2.y) + bflo(v3.y)))
            + ((bflo(v4.y) + bflo(v5.y)) + (bflo(v6.y) + bflo(v7.y)));
        a3 += ((bfhi(v0.y) + bfhi(v1.y)) + (bfhi(v2.y) + bfhi(v3.y)))
            + ((bfhi(v4.y) + bfhi(v5.y)) + (bfhi(v6.y) + bfhi(v7.y)));
    }
    for (; k < e; k += 2) {
        int i0 = csr_src[k];
        uint2 v0 = *(const uint2*)(hc + (size_t)i0 * 128);
        a0 += bflo(v0.x); a1 += bfhi(v0.x);
        a2 += bflo(v0.y); a3 += bfhi(v0.y);
    }

    if constexpr (READOUT) __syncthreads();   // guards sRed reuse across loop iterations

    a0 += __shfl_xor(a0, 8, 64);
    a1 += __shfl_xor(a1, 8, 64);
    a2 += __shfl_xor(a2, 8, 64);
    a3 += __shfl_xor(a3, 8, 64);
    float p0 = __shfl_xor(a0, 1, 64);
    float p1 = __shfl_xor(a1, 1, 64);
    float p2 = __shfl_xor(a2, 1, 64);
    float p3 = __shfl_xor(a3, 1, 64);
    float z[8];
    z[fh * 4 + 0] = a0; z[fh * 4 + 1] = a1; z[fh * 4 + 2] = a2; z[fh * 4 + 3] = a3;
    z[(1 - fh) * 4 + 0] = p0; z[(1 - fh) * 4 + 1] = p1;
    z[(1 - fh) * 4 + 2] = p2; z[(1 - fh) * 4 + 3] = p3;

    float op[8];
    #pragma unroll
    for (int f = 0; f < 8; f++) op[f] = (jgroup == 0) ? sb2[f] : 0.0f;
    #pragma unroll
    for (int jj = 0; jj < 4; jj++) {
        int j = jgroup * 4 + jj;
        float s1 = sb1[j];
        #pragma unroll
        for (int i2 = 0; i2 < 8; i2++) s1 += z[i2] * sW1[i2 * 16 + j];
        s1 = s1 * BN_SCALE * sg1[j] + sbt1[j];
        s1 = gelu_erf(s1);
        #pragma unroll
        for (int f = 0; f < 8; f++) op[f] += s1 * sW2[j * 8 + f];
    }

    if constexpr (!READOUT) {
        float r[4];
        #pragma unroll
        for (int fi = 0; fi < 4; fi++) {
            int f = fh * 4 + fi;
            float x = op[f] + __shfl_xor(op[f], 1, 64);
            x += __shfl_xor(x, 8, 64);
            r[fi] = gelu_erf(x * BN_SCALE * sg2[f] + sbt2[f]);
        }
        if (half == 0) {
            uint2 ou;
            ou.x = pack2(r[0], r[1]); ou.y = pack2(r[2], r[3]);
            *(uint2*)(hout + (size_t)g * 128 + col) = ou;
        }
    } else {
        int b = chunk * 4 + (colpos >> 1);
        float hvh[4];
        #pragma unroll
        for (int fi = 0; fi < 4; fi++) {
            int f = fh * 4 + fi;
            float x = op[f] + __shfl_xor(op[f], 1, 64);
            x += __shfl_xor(x, 8, 64);
            hvh[fi] = gelu_erf(x * BN_SCALE * sg2[f] + sbt2[f]);
        }
        float hv[8];
        #pragma unroll
        for (int fi = 0; fi < 4; fi++) {
            hv[fh * 4 + fi] = hvh[fi];
            hv[(1 - fh) * 4 + fi] = __shfl_xor(hvh[fi], 1, 64);
        }
        float qp = 0.0f;
        #pragma unroll
        for (int jj = 0; jj < 2; jj++) {
            int j = jgroup * 2 + jj;
            float key = sbk[j];
            #pragma unroll
            for (int i2 = 0; i2 < 8; i2++) key += hv[i2] * sWk[i2 * 8 + j];
            qp += key * sWq[j];
        }
        float q = qp + __shfl_xor(qp, 1, 64);
        q += __shfl_xor(q, 8, 64);
        float w = sigmoidf_(q);
        if (fh == 0 && half == 0) w_out[(size_t)b * NGENES + g] = w;

        float contrib[4];
        #pragma unroll
        for (int fi = 0; fi < 4; fi++) {
            int f = fh * 4 + fi;
            float v = sbv[f];
            #pragma unroll
            for (int i2 = 0; i2 < 8; i2++) v += hv[i2] * sWv[i2 * 8 + f];
            contrib[fi] = (half == 0) ? v * w : 0.0f;
        }
        #pragma unroll
        for (int fi = 0; fi < 4; fi++) {
            contrib[fi] += __shfl_xor(contrib[fi], 8, 64);
            contrib[fi] += __shfl_xor(contrib[fi], 16, 64);
            contrib[fi] += __shfl_xor(contrib[fi], 32, 64);
        }
        int wave = t >> 6, lane = t & 63;
        float (*sRed)[4][8] = (float (*)[4][8])sRedRaw;
        if (lane < 8) {
            #pragma unroll
            for (int fi = 0; fi < 4; fi++)
                sRed[wave][lane >> 1][(lane & 1) * 4 + fi] = contrib[fi];
        }
        __syncthreads();
        if (t < 32) {
            int bl = t >> 3, f = t & 7;
            float sm = sRed[0][bl][f] + sRed[1][bl][f] + sRed[2][bl][f] + sRed[3][bl][f];
            partial[(size_t)blk * 32 + bl * 8 + f] = sm;
        }
    }
}

__global__ __launch_bounds__(256, 4) void k_mega(MegaParams p) {
    cg::grid_group grid = cg::this_grid();
    const int t = threadIdx.x;
    const int bid = blockIdx.x;
    const int G = gridDim.x;

    __shared__ float sMLP[352];   // W1(128) W2(128) b1/g1/bt1(16x3) b2/g2/bt2(8x3)
    __shared__ float sAux[152];   // Wk(64) Wv(64) bk(8) bv(8) Wq(8)
    __shared__ float sBig[1408];  // sZ[4][128] | scan ints | sRed[128] | head sgh+z1+z2

    float* sW1 = sMLP;        float* sW2 = sMLP + 128;
    float* sb1 = sMLP + 256;  float* sg1 = sMLP + 272;  float* sbt1 = sMLP + 288;
    float* sb2 = sMLP + 304;  float* sg2 = sMLP + 312;  float* sbt2 = sMLP + 320;
    float* sWk = sAux;        float* sWv = sAux + 64;
    float* sbk = sAux + 128;  float* sbv = sAux + 136;  float* sWq = sAux + 144;

    // ---------------- phase 0: fused 64B node rows + out_filt + node_off + deg zero
    for (int vb = bid; vb < P0A + P0B; vb += G) {
        if (vb < P0A) {
            int n = vb * 256 + t;
            if (n < NSNPS) {
                float f0 = p.filters[0 * NSNPS + n], f1 = p.filters[1 * NSNPS + n];
                float f2 = p.filters[2 * NSNPS + n], f3 = p.filters[3 * NSNPS + n];
                float f4 = p.filters[4 * NSNPS + n], f5 = p.filters[5 * NSNPS + n];
                float f6 = p.filters[6 * NSNPS + n], f7 = p.filters[7 * NSNPS + n];
                p.out_filt[0 * NSNPS + n] = f0; p.out_filt[1 * NSNPS + n] = f1;
                p.out_filt[2 * NSNPS + n] = f2; p.out_filt[3 * NSNPS + n] = f3;
                p.out_filt[4 * NSNPS + n] = f4; p.out_filt[5 * NSNPS + n] = f5;
                p.out_filt[6 * NSNPS + n] = f6; p.out_filt[7 * NSNPS + n] = f7;
                uint4 r0, r1, r2, r3;
                r0.x = pack2(p.snp[0 * (size_t)NSNPS + n],  p.snp[1 * (size_t)NSNPS + n]);
                r0.y = pack2(p.snp[2 * (size_t)NSNPS + n],  p.snp[3 * (size_t)NSNPS + n]);
                r0.z = pack2(p.snp[4 * (size_t)NSNPS + n],  p.snp[5 * (size_t)NSNPS + n]);
                r0.w = pack2(p.snp[6 * (size_t)NSNPS + n],  p.snp[7 * (size_t)NSNPS + n]);
                r1.x = pack2(p.snp[8 * (size_t)NSNPS + n],  p.snp[9 * (size_t)NSNPS + n]);
                r1.y = pack2(p.snp[10 * (size_t)NSNPS + n], p.snp[11 * (size_t)NSNPS + n]);
                r1.z = pack2(p.snp[12 * (size_t)NSNPS + n], p.snp[13 * (size_t)NSNPS + n]);
                r1.w = pack2(p.snp[14 * (size_t)NSNPS + n], p.snp[15 * (size_t)NSNPS + n]);
                r2.x = pack2(f0, f1); r2.y = pack2(f2, f3);
                r2.z = pack2(f4, f5); r2.w = pack2(f6, f7);
                r3.x = r3.y = r3.z = r3.w = 0u;
                uint4* dst = (uint4*)(p.nodeRow + (size_t)n * 32);
                dst[0] = r0; dst[1] = r1; dst[2] = r2; dst[3] = r3;
            }
        } else {
            int g = (vb - P0A) * 256 + t;
            if (g < NGENES) p.deg[g] = 0;
            if (g <= NGENES) {
                int lo = 0, hi = NNODES;
                while (lo < hi) {
                    int mid = (lo + hi) >> 1;
                    if (p.gene_of_node[mid] < g) lo = mid + 1; else hi = mid;
                }
                p.node_off[g] = lo;
            }
        }
    }
    grid.sync();

    // ---------------- phase 1: edge-degree atomics (fast) + snp->gene (long) overlap
    for (int vb = bid; vb < PEDGE + NGENES; vb += G) {
        if (vb < PEDGE) {
            int e = vb * 256 + t;
            if (e < NEDGES) atomicAdd(&p.deg[p.edge_dst[e]], 1);
        } else {
            int g = vb - PEDGE;
            float (*sZ)[128] = (float (*)[128])sBig;
            __syncthreads();                 // sZ reuse guard across iterations
            int wave = t >> 6, lane = t & 63;
            int sub = (wave << 2) + (lane >> 4);
            int b = lane & 15;
            int s = p.node_off[g], ge = p.node_off[g + 1];
            float acc[8];
            #pragma unroll
            for (int f = 0; f < 8; f++) acc[f] = 0.0f;
            int i = s + sub;
            for (; i + 16 < ge; i += 32) {
                int id0 = p.snp_ids[i];
                int id1 = p.snp_ids[i + 16];
                const u16* r0 = p.nodeRow + (size_t)id0 * 32;
                const u16* r1 = p.nodeRow + (size_t)id1 * 32;
                float v0 = bf1(r0[b]);
                float v1 = bf1(r1[b]);
                uint4 F0 = *(const uint4*)(r0 + 16);
                uint4 F1 = *(const uint4*)(r1 + 16);
                acc[0] += v0 * bflo(F0.x) + v1 * bflo(F1.x);
                acc[1] += v0 * bfhi(F0.x) + v1 * bfhi(F1.x);
                acc[2] += v0 * bflo(F0.y) + v1 * bflo(F1.y);
                acc[3] += v0 * bfhi(F0.y) + v1 * bfhi(F1.y);
                acc[4] += v0 * bflo(F0.z) + v1 * bflo(F1.z);
                acc[5] += v0 * bfhi(F0.z) + v1 * bfhi(F1.z);
                acc[6] += v0 * bflo(F0.w) + v1 * bflo(F1.w);
                acc[7] += v0 * bfhi(F0.w) + v1 * bfhi(F1.w);
            }
            if (i < ge) {
                int id0 = p.snp_ids[i];
                const u16* r0 = p.nodeRow + (size_t)id0 * 32;
                float v0 = bf1(r0[b]);
                uint4 F0 = *(const uint4*)(r0 + 16);
                acc[0] += v0 * bflo(F0.x); acc[1] += v0 * bfhi(F0.x);
                acc[2] += v0 * bflo(F0.y); acc[3] += v0 * bfhi(F0.y);
                acc[4] += v0 * bflo(F0.z); acc[5] += v0 * bfhi(F0.z);
                acc[6] += v0 * bflo(F0.w); acc[7] += v0 * bfhi(F0.w);
            }
            #pragma unroll
            for (int f = 0; f < 8; f++) {
                acc[f] += __shfl_xor(acc[f], 16, 64);
                acc[f] += __shfl_xor(acc[f], 32, 64);
            }
            if (lane < 16) {
                float* dst = &sZ[wave][lane * 8];
                *(float4*)(dst)     = make_float4(acc[0], acc[1], acc[2], acc[3]);
                *(float4*)(dst + 4) = make_float4(acc[4], acc[5], acc[6], acc[7]);
            }
            __syncthreads();
            if (t < 128) {
                float val = sZ[0][t] + sZ[1][t] + sZ[2][t] + sZ[3][t];
                p.h0[(size_t)g * 128 + t] = f2bf(val);
            }
        }
    }
    grid.sync();

    // ---------------- phase 2a: per-chunk (256-gene) exclusive scan of deg
    for (int vb = bid; vb < NCHUNK; vb += G) {
        int* sInt = (int*)sBig;
        int g = vb * 256 + t;
        int d = (g < NGENES) ? p.deg[g] : 0;
        __syncthreads();
        sInt[t] = d;
        __syncthreads();
        for (int off = 1; off < 256; off <<= 1) {
            int v = (t >= off) ? sInt[t - off] : 0;
            __syncthreads();
            sInt[t] += v;
            __syncthreads();
        }
        int incl = sInt[t];
        if (g < NGENES) p.csr_off[g] = incl - d;    // exclusive within chunk
        if (t == 255) p.chunkTot[vb] = incl;        // chunk total
    }
    grid.sync();

    // ---------------- phase 2b: wave-scan of 79 chunk totals -> exclusive bases
    if (bid == 0 && t < 64) {
        int a0 = (t < NCHUNK) ? p.chunkTot[t] : 0;
        int a1 = (t + 64 < NCHUNK) ? p.chunkTot[t + 64] : 0;
        int ia = a0, ib = a1;
        #pragma unroll
        for (int m = 1; m < 64; m <<= 1) {
            int v = __shfl_up(ia, m, 64);
            if (t >= m) ia += v;
        }
        int tot0 = __shfl(ia, 63, 64);
        #pragma unroll
        for (int m = 1; m < 64; m <<= 1) {
            int v = __shfl_up(ib, m, 64);
            if (t >= m) ib += v;
        }
        ib += tot0;
        if (t < NCHUNK) p.chunkTot[t] = ia - a0;
        if (t + 64 < NCHUNK) p.chunkTot[t + 64] = ib - a1;
        if (t + 64 == NCHUNK - 1) p.chunkTot[NCHUNK] = ib;   // grand total
    }
    grid.sync();

    // ---------------- phase 2c: add chunk bases -> global csr_off / cursor
    for (int vb = bid; vb < NCHUNK; vb += G) {
        int g = vb * 256 + t;
        if (g < NGENES) {
            int v = p.csr_off[g] + p.chunkTot[vb];
            p.csr_off[g] = v;
            p.cursor[g] = v;
        }
    }
    if (bid == 0 && t == 0) p.csr_off[NGENES] = p.chunkTot[NCHUNK];
    grid.sync();

    // ---------------- phase 3: edge scatter into CSR
    for (int vb = bid; vb < PEDGE; vb += G) {
        int e = vb * 256 + t;
        if (e < NEDGES) {
            int pos = atomicAdd(&p.cursor[p.edge_dst[e]], 1);
            p.csr_src[pos] = p.edge_src[e];
        }
    }
    grid.sync();

    // ---------------- phase 4: GIN layer 1
    if (t < 128) { sW1[t] = p.W1[t]; sW2[t] = p.W2[t]; }
    if (t < 16)  { sb1[t] = p.b1[t]; sg1[t] = p.g1[t]; sbt1[t] = p.bt1[t]; }
    if (t < 8)   { sb2[t] = p.b2[t]; sg2[t] = p.g2[t]; sbt2[t] = p.bt2[t]; }
    __syncthreads();
    {
        float epsv = 1.0f + p.eps[0];
        for (int vb = bid; vb < NBLK2; vb += G)
            gin_body<false>(vb, t, p.h0, p.h1, p.csr_off, p.csr_src, epsv,
                            sW1, sb1, sg1, sbt1, sW2, sb2, sg2, sbt2,
                            nullptr, nullptr, nullptr, nullptr, nullptr,
                            nullptr, nullptr, nullptr);
    }
    grid.sync();

    // ---------------- phase 5: GIN layer 2 + attentive readout partials
    if (t < 128) { sW1[t] = p.W1[128 + t]; sW2[t] = p.W2[128 + t]; }
    if (t < 64)  { sWk[t] = p.Wk[t]; sWv[t] = p.Wv[t]; }
    if (t < 16)  { sb1[t] = p.b1[16 + t]; sg1[t] = p.g1[16 + t]; sbt1[t] = p.bt1[16 + t]; }
    if (t < 8)   { sb2[t] = p.b2[8 + t]; sg2[t] = p.g2[8 + t]; sbt2[t] = p.bt2[8 + t];
                   sbk[t] = p.bk[t]; sbv[t] = p.bv[t]; sWq[t] = p.Wq[t]; }
    __syncthreads();
    {
        float epsv = 1.0f + p.eps[1];
        for (int vb = bid; vb < NBLK2; vb += G)
            gin_body<true>(vb, t, p.h1, nullptr, p.csr_off, p.csr_src, epsv,
                           sW1, sb1, sg1, sbt1, sW2, sb2, sg2, sbt2,
                           sWk, sbk, sWq, sWv, sbv,
                           sBig, p.out_w, p.partial);
    }
    grid.sync();

    // ---------------- phase 6: reduce partial[5000][32] -> g_h[128] (1 wave per bf)
    if (bid < 32) {
        int wave = t >> 6, ln = t & 63;
        int bf = bid * 4 + wave;
        int b = bf >> 3, f = bf & 7;
        int c = b >> 2, bl = b & 3;
        float s = 0.0f;
        for (int j = ln; j < NBLK2 / 4; j += 64)
            s += p.partial[(size_t)(c + 4 * j) * 32 + bl * 8 + f];
        #pragma unroll
        for (int m = 1; m < 64; m <<= 1) s += __shfl_xor(s, m, 64);
        if (ln == 0) p.g_h[bf] = s;
    }
    grid.sync();

    // ---------------- phase 7: head MLP (block 0, 256 threads)
    if (bid == 0) {
        float* sgh = sBig;
        float* z1  = sBig + 128;
        float* z2  = sBig + 1152;
        if (t < 128) sgh[t] = p.g_h[t];
        __syncthreads();
        #pragma unroll
        for (int r = 0; r < 4; r++) {
            int idx = r * 256 + t;
            int b = idx >> 6, j = idx & 63;
            float s = p.bp1[j];
            #pragma unroll
            for (int k = 0; k < 8; k++) s += sgh[b * 8 + k] * p.Wp1[k * 64 + j];
            s = s * BN_SCALE * p.gp1[j] + p.btp1[j];
            z1[idx] = gelu_erf(s);
        }
        __syncthreads();
        {
            int b = t >> 4, j = t & 15;
            float s = p.bp2[j];
            for (int k = 0; k < 64; k++) s += z1[b * 64 + k] * p.Wp2[k * 16 + j];
            s = s * BN_SCALE * p.gp2[j] + p.btp2[j];
            z2[t] = gelu_erf(s);
        }
        __syncthreads();
        if (t < 16) {
            float s = p.bp3[0];
            #pragma unroll
            for (int k = 0; k < 16; k++) s += z2[t * 16 + k] * p.Wp3[k];
            p.out_preds[t] = s;
        }
    }
}

// ===========================================================================
extern "C" void kernel_launch(void* const* d_in, const int* in_sizes, int n_in,
                              void* d_out, int out_size, void* d_ws, size_t ws_size,
                              hipStream_t stream) {
    const float* snp          = (const float*)d_in[0];
    const int*   snp_ids      = (const int*)  d_in[1];
    const int*   gene_of_node = (const int*)  d_in[2];
    const int*   edge_src     = (const int*)  d_in[3];
    const int*   edge_dst     = (const int*)  d_in[4];
    const float* filters      = (const float*)d_in[5];
    const float* eps          = (const float*)d_in[6];
    const float* W1  = (const float*)d_in[7];
    const float* b1  = (const float*)d_in[8];
    const float* g1  = (const float*)d_in[9];
    const float* bt1 = (const float*)d_in[10];
    const float* W2  = (const float*)d_in[11];
    const float* b2  = (const float*)d_in[12];
    const float* g2  = (const float*)d_in[13];
    const float* bt2 = (const float*)d_in[14];
    const float* Wk  = (const float*)d_in[15];
    const float* bk  = (const float*)d_in[16];
    const float* Wq  = (const float*)d_in[17];
    const float* Wv  = (const float*)d_in[18];
    const float* bv  = (const float*)d_in[19];
    const float* Wp1 = (const float*)d_in[20];
    const float* bp1 = (const float*)d_in[21];
    const float* gp1 = (const float*)d_in[22];
    const float* btp1= (const float*)d_in[23];
    const float* Wp2 = (const float*)d_in[24];
    const float* bp2 = (const float*)d_in[25];
    const float* gp2 = (const float*)d_in[26];
    const float* btp2= (const float*)d_in[27];
    const float* Wp3 = (const float*)d_in[28];
    const float* bp3 = (const float*)d_in[29];

    float* out        = (float*)d_out;
    float* out_preds  = out;
    float* out_filt   = out + 16;
    float* out_w      = out + 16 + NFILT * NSNPS;

    // ---- workspace layout (region0 is shared: mega nodeRow | fallback snpT+filtT)
    char* ws = (char*)d_ws;
    size_t off = 0;
    u16* nodeRow = (u16*)(ws + off);                       // 500000*64B = 32 MB
    u16* snpT    = (u16*)(ws + off);                       // fallback alias (16 MB)
    u16* filtT   = (u16*)(ws + off + (size_t)16 * 1024 * 1024);  // fallback alias (8 MB)
    off += (size_t)32 * 1024 * 1024;
    u16* h0   = (u16*)(ws + off); off += (size_t)NGENES * 128 * 2;
    u16* h1   = (u16*)(ws + off); off += (size_t)NGENES * 128 * 2;
    int* node_off = (int*)(ws + off); off += ((NGENES + 1) * 4 + 255) / 256 * 256;
    int* deg      = (int*)(ws + off); off += (NGENES * 4 + 255) / 256 * 256;
    int* csr_off  = (int*)(ws + off); off += ((NGENES + 1) * 4 + 255) / 256 * 256;
    int* cursor   = (int*)(ws + off); off += (NGENES * 4 + 255) / 256 * 256;
    int* chunkTot = (int*)(ws + off); off += 1024;
    int* csr_src  = (int*)(ws + off); off += (size_t)NEDGES * 4;
    float* partial= (float*)(ws + off); off += (size_t)NBLK2 * 32 * 4;
    float* g_h    = (float*)(ws + off); off += 512;

    // ---- primary: single cooperative mega-kernel (1 dispatch, 9 grid syncs)
    MegaParams P;
    P.snp = snp; P.filters = filters; P.eps = eps;
    P.W1 = W1; P.b1 = b1; P.g1 = g1; P.bt1 = bt1;
    P.W2 = W2; P.b2 = b2; P.g2 = g2; P.bt2 = bt2;
    P.Wk = Wk; P.bk = bk; P.Wq = Wq; P.Wv = Wv; P.bv = bv;
    P.Wp1 = Wp1; P.bp1 = bp1; P.gp1 = gp1; P.btp1 = btp1;
    P.Wp2 = Wp2; P.bp2 = bp2; P.gp2 = gp2; P.btp2 = btp2;
    P.Wp3 = Wp3; P.bp3 = bp3;
    P.snp_ids = snp_ids; P.gene_of_node = gene_of_node;
    P.edge_src = edge_src; P.edge_dst = edge_dst;
    P.out_preds = out_preds; P.out_filt = out_filt; P.out_w = out_w;
    P.nodeRow = nodeRow; P.h0 = h0; P.h1 = h1;
    P.node_off = node_off; P.deg = deg; P.csr_off = csr_off;
    P.cursor = cursor; P.chunkTot = chunkTot; P.csr_src = csr_src;
    P.partial = partial; P.g_h = g_h;

    void* kargs[] = { (void*)&P };
    hipError_t err = hipLaunchCooperativeKernel((const void*)k_mega,
                                                dim3(GRID_MEGA), dim3(256),
                                                kargs, 0, stream);
    if (err == hipSuccess) return;
    (void)hipGetLastError();   // clear error, take fallback path

    // ---- fallback: proven 9-kernel pipeline
    k_prep<<<PREP_NA + PREP_NB + PREP_NC, 256, 0, stream>>>(
        snp, filters, gene_of_node, snpT, filtT, out_filt, node_off, deg);
    k_deg<<<(NEDGES + 255) / 256, 256, 0, stream>>>(edge_dst, deg);
    k_scan<<<1, 1024, 0, stream>>>(deg, csr_off, cursor);
    k_scatter<<<(NEDGES + 255) / 256, 256, 0, stream>>>(edge_src, edge_dst, cursor, csr_src);
    k_snp2gene<<<NGENES, 256, 0, stream>>>(snpT, snp_ids, node_off, filtT, h0);
    k_gin1<<<NBLK2, 256, 0, stream>>>(h0, h1, csr_off, csr_src, eps + 0,
                                      W1 + 0 * 128, b1 + 0 * 16, g1 + 0 * 16, bt1 + 0 * 16,
                                      W2 + 0 * 128, b2 + 0 * 8, g2 + 0 * 8, bt2 + 0 * 8);
    k_gin2<<<NBLK2, 256, 0, stream>>>(h1, csr_off, csr_src, eps + 1,
                                      W1 + 1 * 128, b1 + 1 * 16, g1 + 1 * 16, bt1 + 1 * 16,
                                      W2 + 1 * 128, b2 + 1 * 8, g2 + 1 * 8, bt2 + 1 * 8,
                                      Wk, bk, Wq, Wv, bv, out_w, partial);
    k_reduce<<<128, 64, 0, stream>>>(partial, g_h);
    k_head<<<1, 1024, 0, stream>>>(g_h, Wp1, bp1, gp1, btp1, Wp2, bp2, gp2, btp2, Wp3, bp3, out_preds);
}

// Round 2
// 835.361 us; speedup vs baseline: 1.7352x; 1.7352x over previous
//
#include <hip/hip_runtime.h>
#include <math.h>

#define NSNPS  500000
#define NGENES 20000
#define NNODES 600000
#define NEDGES 320000
#define BB     16
#define NFILT  8
#define NBLK2  5000   // gin grid = (NGENES/16)*4

// rsqrt(1 + 1e-5)
#define BN_SCALE 0.99999500003749968f

typedef unsigned short u16;

__device__ __forceinline__ float gelu_erf(float x) {
    return 0.5f * x * (1.0f + erff(x * 0.70710678118654752f));
}
__device__ __forceinline__ float sigmoidf_(float x) {
    return 1.0f / (1.0f + expf(-x));
}
// fp32 -> bf16 round-to-nearest-even
__device__ __forceinline__ u16 f2bf(float x) {
    unsigned u = __float_as_uint(x);
    u += 0x7fffu + ((u >> 16) & 1u);
    return (u16)(u >> 16);
}
__device__ __forceinline__ float bf1(u16 v)      { return __uint_as_float(((unsigned)v) << 16); }
__device__ __forceinline__ float bflo(unsigned v){ return __uint_as_float(v << 16); }
__device__ __forceinline__ float bfhi(unsigned v){ return __uint_as_float(v & 0xffff0000u); }
__device__ __forceinline__ unsigned pack2(float a, float b) {
    return (unsigned)f2bf(a) | ((unsigned)f2bf(b) << 16);
}

// ---------------------------------------------------------------------------
// kA: fused prep.
//   blocks [0, KA_NA)           : 64B nodeRow (snp bf16 x16 | filt bf16 x8 | pad) + out_filt copy
//   blocks [KA_NA, KA_NA+KA_NB) : node_off binary search
//   block  KA_NA+KA_NB          : single-block LDS degree histogram + scan -> csr_off/cursor; done=0
#define KA_NA 1954   // ceil(NSNPS/256)
#define KA_NB 79     // ceil((NGENES+1)/256)
__global__ __launch_bounds__(256) void kA_prep(const float* __restrict__ snp,
                                               const float* __restrict__ filters,
                                               const int* __restrict__ gene_of_node,
                                               const int* __restrict__ edge_dst,
                                               u16* __restrict__ nodeRow,
                                               float* __restrict__ out_filt,
                                               int* __restrict__ node_off,
                                               int* __restrict__ csr_off,
                                               int* __restrict__ cursor,
                                               unsigned* __restrict__ done) {
    __shared__ unsigned sdeg[NGENES / 2];   // packed u16 counter pairs (40 KB)
    __shared__ int ssum[256];
    int bid = blockIdx.x;
    int t = threadIdx.x;

    if (bid < KA_NA) {
        int n = bid * 256 + t;
        if (n < NSNPS) {
            float f0 = filters[0 * NSNPS + n], f1 = filters[1 * NSNPS + n];
            float f2 = filters[2 * NSNPS + n], f3 = filters[3 * NSNPS + n];
            float f4 = filters[4 * NSNPS + n], f5 = filters[5 * NSNPS + n];
            float f6 = filters[6 * NSNPS + n], f7 = filters[7 * NSNPS + n];
            out_filt[0 * NSNPS + n] = f0; out_filt[1 * NSNPS + n] = f1;
            out_filt[2 * NSNPS + n] = f2; out_filt[3 * NSNPS + n] = f3;
            out_filt[4 * NSNPS + n] = f4; out_filt[5 * NSNPS + n] = f5;
            out_filt[6 * NSNPS + n] = f6; out_filt[7 * NSNPS + n] = f7;
            uint4 r0, r1, r2, r3;
            r0.x = pack2(snp[0 * (size_t)NSNPS + n],  snp[1 * (size_t)NSNPS + n]);
            r0.y = pack2(snp[2 * (size_t)NSNPS + n],  snp[3 * (size_t)NSNPS + n]);
            r0.z = pack2(snp[4 * (size_t)NSNPS + n],  snp[5 * (size_t)NSNPS + n]);
            r0.w = pack2(snp[6 * (size_t)NSNPS + n],  snp[7 * (size_t)NSNPS + n]);
            r1.x = pack2(snp[8 * (size_t)NSNPS + n],  snp[9 * (size_t)NSNPS + n]);
            r1.y = pack2(snp[10 * (size_t)NSNPS + n], snp[11 * (size_t)NSNPS + n]);
            r1.z = pack2(snp[12 * (size_t)NSNPS + n], snp[13 * (size_t)NSNPS + n]);
            r1.w = pack2(snp[14 * (size_t)NSNPS + n], snp[15 * (size_t)NSNPS + n]);
            r2.x = pack2(f0, f1); r2.y = pack2(f2, f3);
            r2.z = pack2(f4, f5); r2.w = pack2(f6, f7);
            r3.x = r3.y = r3.z = r3.w = 0u;
            uint4* dst = (uint4*)(nodeRow + (size_t)n * 32);
            dst[0] = r0; dst[1] = r1; dst[2] = r2; dst[3] = r3;
        }
        return;
    }
    if (bid < KA_NA + KA_NB) {
        int g = (bid - KA_NA) * 256 + t;
        if (g <= NGENES) {
            int lo = 0, hi = NNODES;
            while (lo < hi) {
                int mid = (lo + hi) >> 1;
                if (gene_of_node[mid] < g) lo = mid + 1; else hi = mid;
            }
            node_off[g] = lo;
        }
        return;
    }

    // ---- degscan block (256 threads)
    for (int i = t; i < NGENES / 2; i += 256) sdeg[i] = 0u;
    __syncthreads();
    const uint4* ed4 = (const uint4*)edge_dst;
    for (int i = t; i < NEDGES / 4; i += 256) {
        uint4 e4 = ed4[i];
        atomicAdd(&sdeg[e4.x >> 1], (e4.x & 1u) ? 0x10000u : 1u);
        atomicAdd(&sdeg[e4.y >> 1], (e4.y & 1u) ? 0x10000u : 1u);
        atomicAdd(&sdeg[e4.z >> 1], (e4.z & 1u) ? 0x10000u : 1u);
        atomicAdd(&sdeg[e4.w >> 1], (e4.w & 1u) ? 0x10000u : 1u);
    }
    __syncthreads();
    const int CH = 79;                       // 256*79 >= 20000
    int lo = t * CH;
    int hi = lo + CH; if (hi > NGENES) hi = NGENES;
    if (lo > NGENES) lo = NGENES;
    int s = 0;
    for (int g = lo; g < hi; g++) {
        unsigned w = sdeg[g >> 1];
        s += (g & 1) ? (int)(w >> 16) : (int)(w & 0xffffu);
    }
    ssum[t] = s;
    __syncthreads();
    for (int off = 1; off < 256; off <<= 1) {
        int v = (t >= off) ? ssum[t - off] : 0;
        __syncthreads();
        ssum[t] += v;
        __syncthreads();
    }
    int run = (t == 0) ? 0 : ssum[t - 1];
    for (int g = lo; g < hi; g++) {
        unsigned w = sdeg[g >> 1];
        int d = (g & 1) ? (int)(w >> 16) : (int)(w & 0xffffu);
        csr_off[g] = run;
        cursor[g]  = run;
        run += d;
    }
    if (t == 255) csr_off[NGENES] = ssum[255];
    if (t == 0)   *done = 0u;
}

// ---------------------------------------------------------------------------
// kB: edge scatter (blocks [0,1250)) + snp->gene gather (blocks [1250, 1250+NGENES)).
#define KB_SCAT 1250
__global__ __launch_bounds__(256) void kB_gather(const u16* __restrict__ nodeRow,
                                                 const int* __restrict__ snp_ids,
                                                 const int* __restrict__ node_off,
                                                 const int* __restrict__ edge_src,
                                                 const int* __restrict__ edge_dst,
                                                 int* __restrict__ cursor,
                                                 int* __restrict__ csr_src,
                                                 u16* __restrict__ h_bf) {
    int bid = blockIdx.x;
    int t = threadIdx.x;
    if (bid < KB_SCAT) {
        int e = bid * 256 + t;
        if (e < NEDGES) {
            int p = atomicAdd(&cursor[edge_dst[e]], 1);
            csr_src[p] = edge_src[e];
        }
        return;
    }
    __shared__ float sZ[4][128];
    int g = bid - KB_SCAT;
    int wave = t >> 6, lane = t & 63;
    int sub = (wave << 2) + (lane >> 4);     // 0..15
    int b = lane & 15;
    int s = node_off[g], e = node_off[g + 1];

    float acc[8];
    #pragma unroll
    for (int f = 0; f < 8; f++) acc[f] = 0.0f;

    int i = s + sub;
    for (; i + 16 < e; i += 32) {
        int id0 = snp_ids[i];
        int id1 = snp_ids[i + 16];
        const u16* r0 = nodeRow + (size_t)id0 * 32;
        const u16* r1 = nodeRow + (size_t)id1 * 32;
        float v0 = bf1(r0[b]);
        float v1 = bf1(r1[b]);
        uint4 F0 = *(const uint4*)(r0 + 16);
        uint4 F1 = *(const uint4*)(r1 + 16);
        acc[0] += v0 * bflo(F0.x) + v1 * bflo(F1.x);
        acc[1] += v0 * bfhi(F0.x) + v1 * bfhi(F1.x);
        acc[2] += v0 * bflo(F0.y) + v1 * bflo(F1.y);
        acc[3] += v0 * bfhi(F0.y) + v1 * bfhi(F1.y);
        acc[4] += v0 * bflo(F0.z) + v1 * bflo(F1.z);
        acc[5] += v0 * bfhi(F0.z) + v1 * bfhi(F1.z);
        acc[6] += v0 * bflo(F0.w) + v1 * bflo(F1.w);
        acc[7] += v0 * bfhi(F0.w) + v1 * bfhi(F1.w);
    }
    if (i < e) {
        int id0 = snp_ids[i];
        const u16* r0 = nodeRow + (size_t)id0 * 32;
        float v0 = bf1(r0[b]);
        uint4 F0 = *(const uint4*)(r0 + 16);
        acc[0] += v0 * bflo(F0.x); acc[1] += v0 * bfhi(F0.x);
        acc[2] += v0 * bflo(F0.y); acc[3] += v0 * bfhi(F0.y);
        acc[4] += v0 * bflo(F0.z); acc[5] += v0 * bfhi(F0.z);
        acc[6] += v0 * bflo(F0.w); acc[7] += v0 * bfhi(F0.w);
    }
    #pragma unroll
    for (int f = 0; f < 8; f++) {
        acc[f] += __shfl_xor(acc[f], 16, 64);
        acc[f] += __shfl_xor(acc[f], 32, 64);
    }
    if (lane < 16) {   // lane == b
        float* dst = &sZ[wave][lane * 8];
        *(float4*)(dst)     = make_float4(acc[0], acc[1], acc[2], acc[3]);
        *(float4*)(dst + 4) = make_float4(acc[4], acc[5], acc[6], acc[7]);
    }
    __syncthreads();
    if (t < 128) {
        float val = sZ[0][t] + sZ[1][t] + sZ[2][t] + sZ[3][t];
        h_bf[(size_t)g * 128 + t] = f2bf(val);
    }
}

// ---------------------------------------------------------------------------
// kC: GIN layer 1 (verbatim from the proven pipeline).
__global__ __launch_bounds__(256) void kC_gin1(const u16* __restrict__ hin,
                                               u16* __restrict__ hout,
                                               const int* __restrict__ csr_off,
                                               const int* __restrict__ csr_src,
                                               const float* __restrict__ eps_l,
                                               const float* __restrict__ W1,
                                               const float* __restrict__ b1,
                                               const float* __restrict__ g1,
                                               const float* __restrict__ bt1,
                                               const float* __restrict__ W2,
                                               const float* __restrict__ b2,
                                               const float* __restrict__ g2,
                                               const float* __restrict__ bt2) {
    __shared__ float sW1[128], sb1[16], sg1[16], sbt1[16];
    __shared__ float sW2[128], sb2[8], sg2[8], sbt2[8];
    int t = threadIdx.x;
    if (t < 128) { sW1[t] = W1[t]; sW2[t] = W2[t]; }
    if (t < 16)  { sb1[t] = b1[t]; sg1[t] = g1[t]; sbt1[t] = bt1[t]; }
    if (t < 8)   { sb2[t] = b2[t]; sg2[t] = g2[t]; sbt2[t] = bt2[t]; }

    int chunk = blockIdx.x & 3;
    int g = (blockIdx.x >> 2) * 16 + (t >> 4);
    int u = t & 15;
    int half = u >> 3;
    int colpos = u & 7;
    int fh = colpos & 1;
    int jgroup = half * 2 + fh;
    int col = chunk * 32 + colpos * 4;
    const u16* __restrict__ hc = hin + col;
    float epsv = 1.0f + eps_l[0];

    float a0, a1, a2, a3;
    if (half == 0) {
        uint2 su = *(const uint2*)(hc + (size_t)g * 128);
        a0 = bflo(su.x) * epsv; a1 = bfhi(su.x) * epsv;
        a2 = bflo(su.y) * epsv; a3 = bfhi(su.y) * epsv;
    } else {
        a0 = a1 = a2 = a3 = 0.0f;
    }

    int s = csr_off[g], e = csr_off[g + 1];
    int k = s + half;
    for (; k + 14 < e; k += 16) {
        int i0 = csr_src[k],      i1 = csr_src[k + 2];
        int i2 = csr_src[k + 4],  i3 = csr_src[k + 6];
        int i4 = csr_src[k + 8],  i5 = csr_src[k + 10];
        int i6 = csr_src[k + 12], i7 = csr_src[k + 14];
        uint2 v0 = *(const uint2*)(hc + (size_t)i0 * 128);
        uint2 v1 = *(const uint2*)(hc + (size_t)i1 * 128);
        uint2 v2 = *(const uint2*)(hc + (size_t)i2 * 128);
        uint2 v3 = *(const uint2*)(hc + (size_t)i3 * 128);
        uint2 v4 = *(const uint2*)(hc + (size_t)i4 * 128);
        uint2 v5 = *(const uint2*)(hc + (size_t)i5 * 128);
        uint2 v6 = *(const uint2*)(hc + (size_t)i6 * 128);
        uint2 v7 = *(const uint2*)(hc + (size_t)i7 * 128);
        a0 += ((bflo(v0.x) + bflo(v1.x)) + (bflo(v2.x) + bflo(v3.x)))
            + ((bflo(v4.x) + bflo(v5.x)) + (bflo(v6.x) + bflo(v7.x)));
        a1 += ((bfhi(v0.x) + bfhi(v1.x)) + (bfhi(v2.x) + bfhi(v3.x)))
            + ((bfhi(v4.x) + bfhi(v5.x)) + (bfhi(v6.x) + bfhi(v7.x)));
        a2 += ((bflo(v0.y) + bflo(v1.y)) + (bflo(v2.y) + bflo(v3.y)))
            + ((bflo(v4.y) + bflo(v5.y)) + (bflo(v6.y) + bflo(v7.y)));
        a3 += ((bfhi(v0.y) + bfhi(v1.y)) + (bfhi(v2.y) + bfhi(v3.y)))
            + ((bfhi(v4.y) + bfhi(v5.y)) + (bfhi(v6.y) + bfhi(v7.y)));
    }
    for (; k < e; k += 2) {
        int i0 = csr_src[k];
        uint2 v0 = *(const uint2*)(hc + (size_t)i0 * 128);
        a0 += bflo(v0.x); a1 += bfhi(v0.x);
        a2 += bflo(v0.y); a3 += bfhi(v0.y);
    }
    __syncthreads();

    a0 += __shfl_xor(a0, 8, 64);
    a1 += __shfl_xor(a1, 8, 64);
    a2 += __shfl_xor(a2, 8, 64);
    a3 += __shfl_xor(a3, 8, 64);
    float p0 = __shfl_xor(a0, 1, 64);
    float p1 = __shfl_xor(a1, 1, 64);
    float p2 = __shfl_xor(a2, 1, 64);
    float p3 = __shfl_xor(a3, 1, 64);
    float z[8];
    z[fh * 4 + 0] = a0; z[fh * 4 + 1] = a1; z[fh * 4 + 2] = a2; z[fh * 4 + 3] = a3;
    z[(1 - fh) * 4 + 0] = p0; z[(1 - fh) * 4 + 1] = p1;
    z[(1 - fh) * 4 + 2] = p2; z[(1 - fh) * 4 + 3] = p3;

    float op[8];
    #pragma unroll
    for (int f = 0; f < 8; f++) op[f] = (jgroup == 0) ? sb2[f] : 0.0f;
    #pragma unroll
    for (int jj = 0; jj < 4; jj++) {
        int j = jgroup * 4 + jj;
        float s1 = sb1[j];
        #pragma unroll
        for (int i2 = 0; i2 < 8; i2++) s1 += z[i2] * sW1[i2 * 16 + j];
        s1 = s1 * BN_SCALE * sg1[j] + sbt1[j];
        s1 = gelu_erf(s1);
        #pragma unroll
        for (int f = 0; f < 8; f++) op[f] += s1 * sW2[j * 8 + f];
    }
    float r[4];
    #pragma unroll
    for (int fi = 0; fi < 4; fi++) {
        int f = fh * 4 + fi;
        float x = op[f] + __shfl_xor(op[f], 1, 64);
        x += __shfl_xor(x, 8, 64);
        r[fi] = gelu_erf(x * BN_SCALE * sg2[f] + sbt2[f]);
    }
    if (half == 0) {
        uint2 ou;
        ou.x = pack2(r[0], r[1]); ou.y = pack2(r[2], r[3]);
        *(uint2*)(hout + (size_t)g * 128 + col) = ou;
    }
}

// ---------------------------------------------------------------------------
// kD: GIN layer 2 + attentive readout partials + LAST-BLOCK reduce + head MLP.
__global__ __launch_bounds__(256) void kD_gin2(const u16* __restrict__ hin,
                                               const int* __restrict__ csr_off,
                                               const int* __restrict__ csr_src,
                                               const float* __restrict__ eps_l,
                                               const float* __restrict__ W1,
                                               const float* __restrict__ b1,
                                               const float* __restrict__ g1,
                                               const float* __restrict__ bt1,
                                               const float* __restrict__ W2,
                                               const float* __restrict__ b2,
                                               const float* __restrict__ g2,
                                               const float* __restrict__ bt2,
                                               const float* __restrict__ Wk,
                                               const float* __restrict__ bk,
                                               const float* __restrict__ Wq,
                                               const float* __restrict__ Wv,
                                               const float* __restrict__ bv,
                                               float* __restrict__ w_out,
                                               float* __restrict__ partial,
                                               unsigned* __restrict__ done,
                                               const float* __restrict__ Wp1, const float* __restrict__ bp1,
                                               const float* __restrict__ gp1, const float* __restrict__ btp1,
                                               const float* __restrict__ Wp2, const float* __restrict__ bp2,
                                               const float* __restrict__ gp2, const float* __restrict__ btp2,
                                               const float* __restrict__ Wp3, const float* __restrict__ bp3,
                                               float* __restrict__ preds) {
    __shared__ float sW1[128], sb1[16], sg1[16], sbt1[16];
    __shared__ float sW2[128], sb2[8], sg2[8], sbt2[8];
    __shared__ float sWk[64], sWv[64], sbk[8], sbv[8], sWq[8];
    __shared__ float sRed[4][4][8];
    __shared__ float sgh[128];
    __shared__ float z1[1024];
    __shared__ float z2[256];
    __shared__ unsigned sLast;
    int t = threadIdx.x;
    if (t < 128) { sW1[t] = W1[t]; sW2[t] = W2[t]; }
    if (t < 64)  { sWk[t] = Wk[t]; sWv[t] = Wv[t]; }
    if (t < 16)  { sb1[t] = b1[t]; sg1[t] = g1[t]; sbt1[t] = bt1[t]; }
    if (t < 8)   { sb2[t] = b2[t]; sg2[t] = g2[t]; sbt2[t] = bt2[t];
                   sbk[t] = bk[t]; sbv[t] = bv[t]; sWq[t] = Wq[t]; }

    int chunk = blockIdx.x & 3;
    int g = (blockIdx.x >> 2) * 16 + (t >> 4);
    int u = t & 15;
    int half = u >> 3;
    int colpos = u & 7;
    int fh = colpos & 1;
    int jgroup = half * 2 + fh;
    int b = chunk * 4 + (colpos >> 1);
    int col = chunk * 32 + colpos * 4;
    const u16* __restrict__ hc = hin + col;
    float epsv = 1.0f + eps_l[0];

    float a0, a1, a2, a3;
    if (half == 0) {
        uint2 su = *(const uint2*)(hc + (size_t)g * 128);
        a0 = bflo(su.x) * epsv; a1 = bfhi(su.x) * epsv;
        a2 = bflo(su.y) * epsv; a3 = bfhi(su.y) * epsv;
    } else {
        a0 = a1 = a2 = a3 = 0.0f;
    }

    int s = csr_off[g], e = csr_off[g + 1];
    int k = s + half;
    for (; k + 14 < e; k += 16) {
        int i0 = csr_src[k],      i1 = csr_src[k + 2];
        int i2 = csr_src[k + 4],  i3 = csr_src[k + 6];
        int i4 = csr_src[k + 8],  i5 = csr_src[k + 10];
        int i6 = csr_src[k + 12], i7 = csr_src[k + 14];
        uint2 v0 = *(const uint2*)(hc + (size_t)i0 * 128);
        uint2 v1 = *(const uint2*)(hc + (size_t)i1 * 128);
        uint2 v2 = *(const uint2*)(hc + (size_t)i2 * 128);
        uint2 v3 = *(const uint2*)(hc + (size_t)i3 * 128);
        uint2 v4 = *(const uint2*)(hc + (size_t)i4 * 128);
        uint2 v5 = *(const uint2*)(hc + (size_t)i5 * 128);
        uint2 v6 = *(const uint2*)(hc + (size_t)i6 * 128);
        uint2 v7 = *(const uint2*)(hc + (size_t)i7 * 128);
        a0 += ((bflo(v0.x) + bflo(v1.x)) + (bflo(v2.x) + bflo(v3.x)))
            + ((bflo(v4.x) + bflo(v5.x)) + (bflo(v6.x) + bflo(v7.x)));
        a1 += ((bfhi(v0.x) + bfhi(v1.x)) + (bfhi(v2.x) + bfhi(v3.x)))
            + ((bfhi(v4.x) + bfhi(v5.x)) + (bfhi(v6.x) + bfhi(v7.x)));
        a2 += ((bflo(v0.y) + bflo(v1.y)) + (bflo(v2.y) + bflo(v3.y)))
            + ((bflo(v4.y) + bflo(v5.y)) + (bflo(v6.y) + bflo(v7.y)));
        a3 += ((bfhi(v0.y) + bfhi(v1.y)) + (bfhi(v2.y) + bfhi(v3.y)))
            + ((bfhi(v4.y) + bfhi(v5.y)) + (bfhi(v6.y) + bfhi(v7.y)));
    }
    for (; k < e; k += 2) {
        int i0 = csr_src[k];
        uint2 v0 = *(const uint2*)(hc + (size_t)i0 * 128);
        a0 += bflo(v0.x); a1 += bfhi(v0.x);
        a2 += bflo(v0.y); a3 += bfhi(v0.y);
    }
    __syncthreads();

    a0 += __shfl_xor(a0, 8, 64);
    a1 += __shfl_xor(a1, 8, 64);
    a2 += __shfl_xor(a2, 8, 64);
    a3 += __shfl_xor(a3, 8, 64);
    float p0 = __shfl_xor(a0, 1, 64);
    float p1 = __shfl_xor(a1, 1, 64);
    float p2 = __shfl_xor(a2, 1, 64);
    float p3 = __shfl_xor(a3, 1, 64);
    float z[8];
    z[fh * 4 + 0] = a0; z[fh * 4 + 1] = a1; z[fh * 4 + 2] = a2; z[fh * 4 + 3] = a3;
    z[(1 - fh) * 4 + 0] = p0; z[(1 - fh) * 4 + 1] = p1;
    z[(1 - fh) * 4 + 2] = p2; z[(1 - fh) * 4 + 3] = p3;

    float op[8];
    #pragma unroll
    for (int f = 0; f < 8; f++) op[f] = (jgroup == 0) ? sb2[f] : 0.0f;
    #pragma unroll
    for (int jj = 0; jj < 4; jj++) {
        int j = jgroup * 4 + jj;
        float s1 = sb1[j];
        #pragma unroll
        for (int i2 = 0; i2 < 8; i2++) s1 += z[i2] * sW1[i2 * 16 + j];
        s1 = s1 * BN_SCALE * sg1[j] + sbt1[j];
        s1 = gelu_erf(s1);
        #pragma unroll
        for (int f = 0; f < 8; f++) op[f] += s1 * sW2[j * 8 + f];
    }
    float hvh[4];
    #pragma unroll
    for (int fi = 0; fi < 4; fi++) {
        int f = fh * 4 + fi;
        float x = op[f] + __shfl_xor(op[f], 1, 64);
        x += __shfl_xor(x, 8, 64);
        hvh[fi] = gelu_erf(x * BN_SCALE * sg2[f] + sbt2[f]);
    }
    float hv[8];
    #pragma unroll
    for (int fi = 0; fi < 4; fi++) {
        hv[fh * 4 + fi] = hvh[fi];
        hv[(1 - fh) * 4 + fi] = __shfl_xor(hvh[fi], 1, 64);
    }

    float qp = 0.0f;
    #pragma unroll
    for (int jj = 0; jj < 2; jj++) {
        int j = jgroup * 2 + jj;
        float key = sbk[j];
        #pragma unroll
        for (int i2 = 0; i2 < 8; i2++) key += hv[i2] * sWk[i2 * 8 + j];
        qp += key * sWq[j];
    }
    float q = qp + __shfl_xor(qp, 1, 64);
    q += __shfl_xor(q, 8, 64);
    float w = sigmoidf_(q);
    if (fh == 0 && half == 0) w_out[(size_t)b * NGENES + g] = w;

    float contrib[4];
    #pragma unroll
    for (int fi = 0; fi < 4; fi++) {
        int f = fh * 4 + fi;
        float v = sbv[f];
        #pragma unroll
        for (int i2 = 0; i2 < 8; i2++) v += hv[i2] * sWv[i2 * 8 + f];
        contrib[fi] = (half == 0) ? v * w : 0.0f;
    }
    #pragma unroll
    for (int fi = 0; fi < 4; fi++) {
        contrib[fi] += __shfl_xor(contrib[fi], 8, 64);
        contrib[fi] += __shfl_xor(contrib[fi], 16, 64);
        contrib[fi] += __shfl_xor(contrib[fi], 32, 64);
    }
    int wave = t >> 6, lane = t & 63;
    if (lane < 8) {
        #pragma unroll
        for (int fi = 0; fi < 4; fi++)
            sRed[wave][lane >> 1][(lane & 1) * 4 + fi] = contrib[fi];
    }
    __syncthreads();
    if (t < 32) {
        int bl = t >> 3, f = t & 7;
        float sm = sRed[0][bl][f] + sRed[1][bl][f] + sRed[2][bl][f] + sRed[3][bl][f];
        partial[(size_t)blockIdx.x * 32 + bl * 8 + f] = sm;
    }

    // ---- last-block-finishes: reduce partial -> head MLP
    __threadfence();                 // publish this block's partial writes
    __syncthreads();
    if (t == 0) sLast = (atomicAdd(done, 1u) == (unsigned)(NBLK2 - 1)) ? 1u : 0u;
    __syncthreads();
    if (!sLast) return;
    __threadfence();                 // acquire: see all other blocks' partial

    {   // reduce: 4 waves x 32 bf each, bit-identical lane mapping to k_reduce
        int wv = t >> 6, ln = t & 63;
        for (int bfi = 0; bfi < 32; bfi++) {
            int bf = wv * 32 + bfi;
            int bb = bf >> 3, f = bf & 7;
            int c = bb >> 2, bl = bb & 3;
            float s2 = 0.0f;
            for (int j = ln; j < NBLK2 / 4; j += 64)
                s2 += partial[(size_t)(c + 4 * j) * 32 + bl * 8 + f];
            #pragma unroll
            for (int m = 1; m < 64; m <<= 1) s2 += __shfl_xor(s2, m, 64);
            if (ln == 0) sgh[bf] = s2;
        }
    }
    __syncthreads();
    #pragma unroll
    for (int r = 0; r < 4; r++) {
        int idx = r * 256 + t;
        int bb = idx >> 6, j = idx & 63;
        float s2 = bp1[j];
        #pragma unroll
        for (int kk = 0; kk < 8; kk++) s2 += sgh[bb * 8 + kk] * Wp1[kk * 64 + j];
        s2 = s2 * BN_SCALE * gp1[j] + btp1[j];
        z1[idx] = gelu_erf(s2);
    }
    __syncthreads();
    {
        int bb = t >> 4, j = t & 15;
        float s2 = bp2[j];
        for (int kk = 0; kk < 64; kk++) s2 += z1[bb * 64 + kk] * Wp2[kk * 16 + j];
        s2 = s2 * BN_SCALE * gp2[j] + btp2[j];
        z2[t] = gelu_erf(s2);
    }
    __syncthreads();
    if (t < 16) {
        float s2 = bp3[0];
        #pragma unroll
        for (int kk = 0; kk < 16; kk++) s2 += z2[t * 16 + kk] * Wp3[kk];
        preds[t] = s2;
    }
}

// ---------------------------------------------------------------------------
extern "C" void kernel_launch(void* const* d_in, const int* in_sizes, int n_in,
                              void* d_out, int out_size, void* d_ws, size_t ws_size,
                              hipStream_t stream) {
    const float* snp          = (const float*)d_in[0];
    const int*   snp_ids      = (const int*)  d_in[1];
    const int*   gene_of_node = (const int*)  d_in[2];
    const int*   edge_src     = (const int*)  d_in[3];
    const int*   edge_dst     = (const int*)  d_in[4];
    const float* filters      = (const float*)d_in[5];
    const float* eps          = (const float*)d_in[6];
    const float* W1  = (const float*)d_in[7];
    const float* b1  = (const float*)d_in[8];
    const float* g1  = (const float*)d_in[9];
    const float* bt1 = (const float*)d_in[10];
    const float* W2  = (const float*)d_in[11];
    const float* b2  = (const float*)d_in[12];
    const float* g2  = (const float*)d_in[13];
    const float* bt2 = (const float*)d_in[14];
    const float* Wk  = (const float*)d_in[15];
    const float* bk  = (const float*)d_in[16];
    const float* Wq  = (const float*)d_in[17];
    const float* Wv  = (const float*)d_in[18];
    const float* bv  = (const float*)d_in[19];
    const float* Wp1 = (const float*)d_in[20];
    const float* bp1 = (const float*)d_in[21];
    const float* gp1 = (const float*)d_in[22];
    const float* btp1= (const float*)d_in[23];
    const float* Wp2 = (const float*)d_in[24];
    const float* bp2 = (const float*)d_in[25];
    const float* gp2 = (const float*)d_in[26];
    const float* btp2= (const float*)d_in[27];
    const float* Wp3 = (const float*)d_in[28];
    const float* bp3 = (const float*)d_in[29];

    float* out        = (float*)d_out;
    float* out_preds  = out;
    float* out_filt   = out + 16;
    float* out_w      = out + 16 + NFILT * NSNPS;

    // ---- workspace layout
    char* ws = (char*)d_ws;
    size_t off = 0;
    u16* nodeRow = (u16*)(ws + off); off += (size_t)NSNPS * 64;                  // 32 MB
    u16* h0   = (u16*)(ws + off); off += (size_t)NGENES * 128 * 2;               // 5.12 MB
    u16* h1   = (u16*)(ws + off); off += (size_t)NGENES * 128 * 2;               // 5.12 MB
    int* node_off = (int*)(ws + off); off += ((NGENES + 1) * 4 + 255) / 256 * 256;
    int* csr_off  = (int*)(ws + off); off += ((NGENES + 1) * 4 + 255) / 256 * 256;
    int* cursor   = (int*)(ws + off); off += (NGENES * 4 + 255) / 256 * 256;
    int* csr_src  = (int*)(ws + off); off += (size_t)NEDGES * 4;
    float* partial= (float*)(ws + off); off += (size_t)NBLK2 * 32 * 4;           // 640 KB
    unsigned* done= (unsigned*)(ws + off); off += 256;

    // 1. fused prep: node rows + out_filt + node_off + single-block degscan (csr_off/cursor, done=0)
    kA_prep<<<KA_NA + KA_NB + 1, 256, 0, stream>>>(
        snp, filters, gene_of_node, edge_dst, nodeRow, out_filt, node_off, csr_off, cursor, done);
    // 2. edge scatter + snp->gene gather (independent halves, one dispatch)
    kB_gather<<<KB_SCAT + NGENES, 256, 0, stream>>>(
        nodeRow, snp_ids, node_off, edge_src, edge_dst, cursor, csr_src, h0);
    // 3. GIN layer 1
    kC_gin1<<<NBLK2, 256, 0, stream>>>(h0, h1, csr_off, csr_src, eps + 0,
                                       W1 + 0 * 128, b1 + 0 * 16, g1 + 0 * 16, bt1 + 0 * 16,
                                       W2 + 0 * 128, b2 + 0 * 8, g2 + 0 * 8, bt2 + 0 * 8);
    // 4. GIN layer 2 + readout + last-block reduce+head
    kD_gin2<<<NBLK2, 256, 0, stream>>>(h1, csr_off, csr_src, eps + 1,
                                       W1 + 1 * 128, b1 + 1 * 16, g1 + 1 * 16, bt1 + 1 * 16,
                                       W2 + 1 * 128, b2 + 1 * 8, g2 + 1 * 8, bt2 + 1 * 8,
                                       Wk, bk, Wq, Wv, bv, out_w, partial, done,
                                       Wp1, bp1, gp1, btp1, Wp2, bp2, gp2, btp2, Wp3, bp3, out_preds);
}

// Round 3
// 405.799 us; speedup vs baseline: 3.5721x; 2.0586x over previous
//
#include <hip/hip_runtime.h>
#include <math.h>

#define NSNPS  500000
#define NGENES 20000
#define NNODES 600000
#define NEDGES 320000
#define BB     16
#define NFILT  8
#define NBLK2  5000   // gin grid = (NGENES/16)*4

// rsqrt(1 + 1e-5)
#define BN_SCALE 0.99999500003749968f

typedef unsigned short u16;

__device__ __forceinline__ float gelu_erf(float x) {
    return 0.5f * x * (1.0f + erff(x * 0.70710678118654752f));
}
__device__ __forceinline__ float sigmoidf_(float x) {
    return 1.0f / (1.0f + expf(-x));
}
// fp32 -> bf16 round-to-nearest-even
__device__ __forceinline__ u16 f2bf(float x) {
    unsigned u = __float_as_uint(x);
    u += 0x7fffu + ((u >> 16) & 1u);
    return (u16)(u >> 16);
}
__device__ __forceinline__ float bf1(u16 v)      { return __uint_as_float(((unsigned)v) << 16); }
__device__ __forceinline__ float bflo(unsigned v){ return __uint_as_float(v << 16); }
__device__ __forceinline__ float bfhi(unsigned v){ return __uint_as_float(v & 0xffff0000u); }
__device__ __forceinline__ unsigned pack2(float a, float b) {
    return (unsigned)f2bf(a) | ((unsigned)f2bf(b) << 16);
}

// ---------------------------------------------------------------------------
// kA: fused prep.
//   blocks [0, KA_NA)           : 64B nodeRow (snp bf16 x16 | filt bf16 x8 | pad) + out_filt copy
//   blocks [KA_NA, KA_NA+KA_NB) : node_off binary search
//   block  KA_NA+KA_NB          : single-block LDS degree histogram (16-deep load ILP)
//                                 + scan -> csr_off/cursor
#define KA_NA 1954   // ceil(NSNPS/256)
#define KA_NB 79     // ceil((NGENES+1)/256)
__global__ __launch_bounds__(256) void kA_prep(const float* __restrict__ snp,
                                               const float* __restrict__ filters,
                                               const int* __restrict__ gene_of_node,
                                               const int* __restrict__ edge_dst,
                                               u16* __restrict__ nodeRow,
                                               float* __restrict__ out_filt,
                                               int* __restrict__ node_off,
                                               int* __restrict__ csr_off,
                                               int* __restrict__ cursor) {
    __shared__ unsigned sdeg[NGENES / 2];   // packed u16 counter pairs (40 KB)
    __shared__ int ssum[256];
    int bid = blockIdx.x;
    int t = threadIdx.x;

    if (bid < KA_NA) {
        int n = bid * 256 + t;
        if (n < NSNPS) {
            float f0 = filters[0 * NSNPS + n], f1 = filters[1 * NSNPS + n];
            float f2 = filters[2 * NSNPS + n], f3 = filters[3 * NSNPS + n];
            float f4 = filters[4 * NSNPS + n], f5 = filters[5 * NSNPS + n];
            float f6 = filters[6 * NSNPS + n], f7 = filters[7 * NSNPS + n];
            out_filt[0 * NSNPS + n] = f0; out_filt[1 * NSNPS + n] = f1;
            out_filt[2 * NSNPS + n] = f2; out_filt[3 * NSNPS + n] = f3;
            out_filt[4 * NSNPS + n] = f4; out_filt[5 * NSNPS + n] = f5;
            out_filt[6 * NSNPS + n] = f6; out_filt[7 * NSNPS + n] = f7;
            uint4 r0, r1, r2, r3;
            r0.x = pack2(snp[0 * (size_t)NSNPS + n],  snp[1 * (size_t)NSNPS + n]);
            r0.y = pack2(snp[2 * (size_t)NSNPS + n],  snp[3 * (size_t)NSNPS + n]);
            r0.z = pack2(snp[4 * (size_t)NSNPS + n],  snp[5 * (size_t)NSNPS + n]);
            r0.w = pack2(snp[6 * (size_t)NSNPS + n],  snp[7 * (size_t)NSNPS + n]);
            r1.x = pack2(snp[8 * (size_t)NSNPS + n],  snp[9 * (size_t)NSNPS + n]);
            r1.y = pack2(snp[10 * (size_t)NSNPS + n], snp[11 * (size_t)NSNPS + n]);
            r1.z = pack2(snp[12 * (size_t)NSNPS + n], snp[13 * (size_t)NSNPS + n]);
            r1.w = pack2(snp[14 * (size_t)NSNPS + n], snp[15 * (size_t)NSNPS + n]);
            r2.x = pack2(f0, f1); r2.y = pack2(f2, f3);
            r2.z = pack2(f4, f5); r2.w = pack2(f6, f7);
            r3.x = r3.y = r3.z = r3.w = 0u;
            uint4* dst = (uint4*)(nodeRow + (size_t)n * 32);
            dst[0] = r0; dst[1] = r1; dst[2] = r2; dst[3] = r3;
        }
        return;
    }
    if (bid < KA_NA + KA_NB) {
        int g = (bid - KA_NA) * 256 + t;
        if (g <= NGENES) {
            int lo = 0, hi = NNODES;
            while (lo < hi) {
                int mid = (lo + hi) >> 1;
                if (gene_of_node[mid] < g) lo = mid + 1; else hi = mid;
            }
            node_off[g] = lo;
        }
        return;
    }

    // ---- degscan block (256 threads, 16-deep load ILP)
    for (int i = t; i < NGENES / 2; i += 256) sdeg[i] = 0u;
    __syncthreads();
    const uint4* ed4 = (const uint4*)edge_dst;
    const int NE4 = NEDGES / 4;              // 80000
    for (int base = 0; base < NE4; base += 256 * 16) {
        uint4 v[16];
        #pragma unroll
        for (int u = 0; u < 16; u++) {
            int idx = base + u * 256 + t;
            if (idx < NE4) v[u] = ed4[idx];
        }
        #pragma unroll
        for (int u = 0; u < 16; u++) {
            int idx = base + u * 256 + t;
            if (idx < NE4) {
                atomicAdd(&sdeg[v[u].x >> 1], (v[u].x & 1u) ? 0x10000u : 1u);
                atomicAdd(&sdeg[v[u].y >> 1], (v[u].y & 1u) ? 0x10000u : 1u);
                atomicAdd(&sdeg[v[u].z >> 1], (v[u].z & 1u) ? 0x10000u : 1u);
                atomicAdd(&sdeg[v[u].w >> 1], (v[u].w & 1u) ? 0x10000u : 1u);
            }
        }
    }
    __syncthreads();
    const int CH = 79;                       // 256*79 >= 20000
    int lo = t * CH;
    int hi = lo + CH; if (hi > NGENES) hi = NGENES;
    if (lo > NGENES) lo = NGENES;
    int s = 0;
    for (int g = lo; g < hi; g++) {
        unsigned w = sdeg[g >> 1];
        s += (g & 1) ? (int)(w >> 16) : (int)(w & 0xffffu);
    }
    ssum[t] = s;
    __syncthreads();
    for (int off = 1; off < 256; off <<= 1) {
        int v = (t >= off) ? ssum[t - off] : 0;
        __syncthreads();
        ssum[t] += v;
        __syncthreads();
    }
    int run = (t == 0) ? 0 : ssum[t - 1];
    for (int g = lo; g < hi; g++) {
        unsigned w = sdeg[g >> 1];
        int d = (g & 1) ? (int)(w >> 16) : (int)(w & 0xffffu);
        csr_off[g] = run;
        cursor[g]  = run;
        run += d;
    }
    if (t == 255) csr_off[NGENES] = ssum[255];
}

// ---------------------------------------------------------------------------
// kB: snp->gene gather (blocks [0, NGENES)) + edge scatter (blocks [NGENES, NGENES+1250)).
// Gather first: it is the long pole, so it starts scheduling earliest.
#define KB_SCAT 1250
__global__ __launch_bounds__(256) void kB_gather(const u16* __restrict__ nodeRow,
                                                 const int* __restrict__ snp_ids,
                                                 const int* __restrict__ node_off,
                                                 const int* __restrict__ edge_src,
                                                 const int* __restrict__ edge_dst,
                                                 int* __restrict__ cursor,
                                                 int* __restrict__ csr_src,
                                                 u16* __restrict__ h_bf) {
    int bid = blockIdx.x;
    int t = threadIdx.x;
    if (bid >= NGENES) {
        int e = (bid - NGENES) * 256 + t;
        if (e < NEDGES) {
            int p = atomicAdd(&cursor[edge_dst[e]], 1);
            csr_src[p] = edge_src[e];
        }
        return;
    }
    __shared__ float sZ[4][128];
    int g = bid;
    int wave = t >> 6, lane = t & 63;
    int sub = (wave << 2) + (lane >> 4);     // 0..15
    int b = lane & 15;
    int s = node_off[g], e = node_off[g + 1];

    float acc[8];
    #pragma unroll
    for (int f = 0; f < 8; f++) acc[f] = 0.0f;

    int i = s + sub;
    for (; i + 16 < e; i += 32) {
        int id0 = snp_ids[i];
        int id1 = snp_ids[i + 16];
        const u16* r0 = nodeRow + (size_t)id0 * 32;
        const u16* r1 = nodeRow + (size_t)id1 * 32;
        float v0 = bf1(r0[b]);
        float v1 = bf1(r1[b]);
        uint4 F0 = *(const uint4*)(r0 + 16);
        uint4 F1 = *(const uint4*)(r1 + 16);
        acc[0] += v0 * bflo(F0.x) + v1 * bflo(F1.x);
        acc[1] += v0 * bfhi(F0.x) + v1 * bfhi(F1.x);
        acc[2] += v0 * bflo(F0.y) + v1 * bflo(F1.y);
        acc[3] += v0 * bfhi(F0.y) + v1 * bfhi(F1.y);
        acc[4] += v0 * bflo(F0.z) + v1 * bflo(F1.z);
        acc[5] += v0 * bfhi(F0.z) + v1 * bfhi(F1.z);
        acc[6] += v0 * bflo(F0.w) + v1 * bflo(F1.w);
        acc[7] += v0 * bfhi(F0.w) + v1 * bfhi(F1.w);
    }
    if (i < e) {
        int id0 = snp_ids[i];
        const u16* r0 = nodeRow + (size_t)id0 * 32;
        float v0 = bf1(r0[b]);
        uint4 F0 = *(const uint4*)(r0 + 16);
        acc[0] += v0 * bflo(F0.x); acc[1] += v0 * bfhi(F0.x);
        acc[2] += v0 * bflo(F0.y); acc[3] += v0 * bfhi(F0.y);
        acc[4] += v0 * bflo(F0.z); acc[5] += v0 * bfhi(F0.z);
        acc[6] += v0 * bflo(F0.w); acc[7] += v0 * bfhi(F0.w);
    }
    #pragma unroll
    for (int f = 0; f < 8; f++) {
        acc[f] += __shfl_xor(acc[f], 16, 64);
        acc[f] += __shfl_xor(acc[f], 32, 64);
    }
    if (lane < 16) {   // lane == b
        float* dst = &sZ[wave][lane * 8];
        *(float4*)(dst)     = make_float4(acc[0], acc[1], acc[2], acc[3]);
        *(float4*)(dst + 4) = make_float4(acc[4], acc[5], acc[6], acc[7]);
    }
    __syncthreads();
    if (t < 128) {
        float val = sZ[0][t] + sZ[1][t] + sZ[2][t] + sZ[3][t];
        h_bf[(size_t)g * 128 + t] = f2bf(val);
    }
}

// ---------------------------------------------------------------------------
// kC: GIN layer 1 (verbatim from the proven pipeline).
__global__ __launch_bounds__(256) void kC_gin1(const u16* __restrict__ hin,
                                               u16* __restrict__ hout,
                                               const int* __restrict__ csr_off,
                                               const int* __restrict__ csr_src,
                                               const float* __restrict__ eps_l,
                                               const float* __restrict__ W1,
                                               const float* __restrict__ b1,
                                               const float* __restrict__ g1,
                                               const float* __restrict__ bt1,
                                               const float* __restrict__ W2,
                                               const float* __restrict__ b2,
                                               const float* __restrict__ g2,
                                               const float* __restrict__ bt2) {
    __shared__ float sW1[128], sb1[16], sg1[16], sbt1[16];
    __shared__ float sW2[128], sb2[8], sg2[8], sbt2[8];
    int t = threadIdx.x;
    if (t < 128) { sW1[t] = W1[t]; sW2[t] = W2[t]; }
    if (t < 16)  { sb1[t] = b1[t]; sg1[t] = g1[t]; sbt1[t] = bt1[t]; }
    if (t < 8)   { sb2[t] = b2[t]; sg2[t] = g2[t]; sbt2[t] = bt2[t]; }

    int chunk = blockIdx.x & 3;
    int g = (blockIdx.x >> 2) * 16 + (t >> 4);
    int u = t & 15;
    int half = u >> 3;
    int colpos = u & 7;
    int fh = colpos & 1;
    int jgroup = half * 2 + fh;
    int col = chunk * 32 + colpos * 4;
    const u16* __restrict__ hc = hin + col;
    float epsv = 1.0f + eps_l[0];

    float a0, a1, a2, a3;
    if (half == 0) {
        uint2 su = *(const uint2*)(hc + (size_t)g * 128);
        a0 = bflo(su.x) * epsv; a1 = bfhi(su.x) * epsv;
        a2 = bflo(su.y) * epsv; a3 = bfhi(su.y) * epsv;
    } else {
        a0 = a1 = a2 = a3 = 0.0f;
    }

    int s = csr_off[g], e = csr_off[g + 1];
    int k = s + half;
    for (; k + 14 < e; k += 16) {
        int i0 = csr_src[k],      i1 = csr_src[k + 2];
        int i2 = csr_src[k + 4],  i3 = csr_src[k + 6];
        int i4 = csr_src[k + 8],  i5 = csr_src[k + 10];
        int i6 = csr_src[k + 12], i7 = csr_src[k + 14];
        uint2 v0 = *(const uint2*)(hc + (size_t)i0 * 128);
        uint2 v1 = *(const uint2*)(hc + (size_t)i1 * 128);
        uint2 v2 = *(const uint2*)(hc + (size_t)i2 * 128);
        uint2 v3 = *(const uint2*)(hc + (size_t)i3 * 128);
        uint2 v4 = *(const uint2*)(hc + (size_t)i4 * 128);
        uint2 v5 = *(const uint2*)(hc + (size_t)i5 * 128);
        uint2 v6 = *(const uint2*)(hc + (size_t)i6 * 128);
        uint2 v7 = *(const uint2*)(hc + (size_t)i7 * 128);
        a0 += ((bflo(v0.x) + bflo(v1.x)) + (bflo(v2.x) + bflo(v3.x)))
            + ((bflo(v4.x) + bflo(v5.x)) + (bflo(v6.x) + bflo(v7.x)));
        a1 += ((bfhi(v0.x) + bfhi(v1.x)) + (bfhi(v2.x) + bfhi(v3.x)))
            + ((bfhi(v4.x) + bfhi(v5.x)) + (bfhi(v6.x) + bfhi(v7.x)));
        a2 += ((bflo(v0.y) + bflo(v1.y)) + (bflo(v2.y) + bflo(v3.y)))
            + ((bflo(v4.y) + bflo(v5.y)) + (bflo(v6.y) + bflo(v7.y)));
        a3 += ((bfhi(v0.y) + bfhi(v1.y)) + (bfhi(v2.y) + bfhi(v3.y)))
            + ((bfhi(v4.y) + bfhi(v5.y)) + (bfhi(v6.y) + bfhi(v7.y)));
    }
    for (; k < e; k += 2) {
        int i0 = csr_src[k];
        uint2 v0 = *(const uint2*)(hc + (size_t)i0 * 128);
        a0 += bflo(v0.x); a1 += bfhi(v0.x);
        a2 += bflo(v0.y); a3 += bfhi(v0.y);
    }
    __syncthreads();

    a0 += __shfl_xor(a0, 8, 64);
    a1 += __shfl_xor(a1, 8, 64);
    a2 += __shfl_xor(a2, 8, 64);
    a3 += __shfl_xor(a3, 8, 64);
    float p0 = __shfl_xor(a0, 1, 64);
    float p1 = __shfl_xor(a1, 1, 64);
    float p2 = __shfl_xor(a2, 1, 64);
    float p3 = __shfl_xor(a3, 1, 64);
    float z[8];
    z[fh * 4 + 0] = a0; z[fh * 4 + 1] = a1; z[fh * 4 + 2] = a2; z[fh * 4 + 3] = a3;
    z[(1 - fh) * 4 + 0] = p0; z[(1 - fh) * 4 + 1] = p1;
    z[(1 - fh) * 4 + 2] = p2; z[(1 - fh) * 4 + 3] = p3;

    float op[8];
    #pragma unroll
    for (int f = 0; f < 8; f++) op[f] = (jgroup == 0) ? sb2[f] : 0.0f;
    #pragma unroll
    for (int jj = 0; jj < 4; jj++) {
        int j = jgroup * 4 + jj;
        float s1 = sb1[j];
        #pragma unroll
        for (int i2 = 0; i2 < 8; i2++) s1 += z[i2] * sW1[i2 * 16 + j];
        s1 = s1 * BN_SCALE * sg1[j] + sbt1[j];
        s1 = gelu_erf(s1);
        #pragma unroll
        for (int f = 0; f < 8; f++) op[f] += s1 * sW2[j * 8 + f];
    }
    float r[4];
    #pragma unroll
    for (int fi = 0; fi < 4; fi++) {
        int f = fh * 4 + fi;
        float x = op[f] + __shfl_xor(op[f], 1, 64);
        x += __shfl_xor(x, 8, 64);
        r[fi] = gelu_erf(x * BN_SCALE * sg2[f] + sbt2[f]);
    }
    if (half == 0) {
        uint2 ou;
        ou.x = pack2(r[0], r[1]); ou.y = pack2(r[2], r[3]);
        *(uint2*)(hout + (size_t)g * 128 + col) = ou;
    }
}

// ---------------------------------------------------------------------------
// kD: GIN layer 2 + attentive readout partials (plain — no fences, no counters).
__global__ __launch_bounds__(256) void kD_gin2(const u16* __restrict__ hin,
                                               const int* __restrict__ csr_off,
                                               const int* __restrict__ csr_src,
                                               const float* __restrict__ eps_l,
                                               const float* __restrict__ W1,
                                               const float* __restrict__ b1,
                                               const float* __restrict__ g1,
                                               const float* __restrict__ bt1,
                                               const float* __restrict__ W2,
                                               const float* __restrict__ b2,
                                               const float* __restrict__ g2,
                                               const float* __restrict__ bt2,
                                               const float* __restrict__ Wk,
                                               const float* __restrict__ bk,
                                               const float* __restrict__ Wq,
                                               const float* __restrict__ Wv,
                                               const float* __restrict__ bv,
                                               float* __restrict__ w_out,
                                               float* __restrict__ partial) {
    __shared__ float sW1[128], sb1[16], sg1[16], sbt1[16];
    __shared__ float sW2[128], sb2[8], sg2[8], sbt2[8];
    __shared__ float sWk[64], sWv[64], sbk[8], sbv[8], sWq[8];
    __shared__ float sRed[4][4][8];
    int t = threadIdx.x;
    if (t < 128) { sW1[t] = W1[t]; sW2[t] = W2[t]; }
    if (t < 64)  { sWk[t] = Wk[t]; sWv[t] = Wv[t]; }
    if (t < 16)  { sb1[t] = b1[t]; sg1[t] = g1[t]; sbt1[t] = bt1[t]; }
    if (t < 8)   { sb2[t] = b2[t]; sg2[t] = g2[t]; sbt2[t] = bt2[t];
                   sbk[t] = bk[t]; sbv[t] = bv[t]; sWq[t] = Wq[t]; }

    int chunk = blockIdx.x & 3;
    int g = (blockIdx.x >> 2) * 16 + (t >> 4);
    int u = t & 15;
    int half = u >> 3;
    int colpos = u & 7;
    int fh = colpos & 1;
    int jgroup = half * 2 + fh;
    int b = chunk * 4 + (colpos >> 1);
    int col = chunk * 32 + colpos * 4;
    const u16* __restrict__ hc = hin + col;
    float epsv = 1.0f + eps_l[0];

    float a0, a1, a2, a3;
    if (half == 0) {
        uint2 su = *(const uint2*)(hc + (size_t)g * 128);
        a0 = bflo(su.x) * epsv; a1 = bfhi(su.x) * epsv;
        a2 = bflo(su.y) * epsv; a3 = bfhi(su.y) * epsv;
    } else {
        a0 = a1 = a2 = a3 = 0.0f;
    }

    int s = csr_off[g], e = csr_off[g + 1];
    int k = s + half;
    for (; k + 14 < e; k += 16) {
        int i0 = csr_src[k],      i1 = csr_src[k + 2];
        int i2 = csr_src[k + 4],  i3 = csr_src[k + 6];
        int i4 = csr_src[k + 8],  i5 = csr_src[k + 10];
        int i6 = csr_src[k + 12], i7 = csr_src[k + 14];
        uint2 v0 = *(const uint2*)(hc + (size_t)i0 * 128);
        uint2 v1 = *(const uint2*)(hc + (size_t)i1 * 128);
        uint2 v2 = *(const uint2*)(hc + (size_t)i2 * 128);
        uint2 v3 = *(const uint2*)(hc + (size_t)i3 * 128);
        uint2 v4 = *(const uint2*)(hc + (size_t)i4 * 128);
        uint2 v5 = *(const uint2*)(hc + (size_t)i5 * 128);
        uint2 v6 = *(const uint2*)(hc + (size_t)i6 * 128);
        uint2 v7 = *(const uint2*)(hc + (size_t)i7 * 128);
        a0 += ((bflo(v0.x) + bflo(v1.x)) + (bflo(v2.x) + bflo(v3.x)))
            + ((bflo(v4.x) + bflo(v5.x)) + (bflo(v6.x) + bflo(v7.x)));
        a1 += ((bfhi(v0.x) + bfhi(v1.x)) + (bfhi(v2.x) + bfhi(v3.x)))
            + ((bfhi(v4.x) + bfhi(v5.x)) + (bfhi(v6.x) + bfhi(v7.x)));
        a2 += ((bflo(v0.y) + bflo(v1.y)) + (bflo(v2.y) + bflo(v3.y)))
            + ((bflo(v4.y) + bflo(v5.y)) + (bflo(v6.y) + bflo(v7.y)));
        a3 += ((bfhi(v0.y) + bfhi(v1.y)) + (bfhi(v2.y) + bfhi(v3.y)))
            + ((bfhi(v4.y) + bfhi(v5.y)) + (bfhi(v6.y) + bfhi(v7.y)));
    }
    for (; k < e; k += 2) {
        int i0 = csr_src[k];
        uint2 v0 = *(const uint2*)(hc + (size_t)i0 * 128);
        a0 += bflo(v0.x); a1 += bfhi(v0.x);
        a2 += bflo(v0.y); a3 += bfhi(v0.y);
    }
    __syncthreads();

    a0 += __shfl_xor(a0, 8, 64);
    a1 += __shfl_xor(a1, 8, 64);
    a2 += __shfl_xor(a2, 8, 64);
    a3 += __shfl_xor(a3, 8, 64);
    float p0 = __shfl_xor(a0, 1, 64);
    float p1 = __shfl_xor(a1, 1, 64);
    float p2 = __shfl_xor(a2, 1, 64);
    float p3 = __shfl_xor(a3, 1, 64);
    float z[8];
    z[fh * 4 + 0] = a0; z[fh * 4 + 1] = a1; z[fh * 4 + 2] = a2; z[fh * 4 + 3] = a3;
    z[(1 - fh) * 4 + 0] = p0; z[(1 - fh) * 4 + 1] = p1;
    z[(1 - fh) * 4 + 2] = p2; z[(1 - fh) * 4 + 3] = p3;

    float op[8];
    #pragma unroll
    for (int f = 0; f < 8; f++) op[f] = (jgroup == 0) ? sb2[f] : 0.0f;
    #pragma unroll
    for (int jj = 0; jj < 4; jj++) {
        int j = jgroup * 4 + jj;
        float s1 = sb1[j];
        #pragma unroll
        for (int i2 = 0; i2 < 8; i2++) s1 += z[i2] * sW1[i2 * 16 + j];
        s1 = s1 * BN_SCALE * sg1[j] + sbt1[j];
        s1 = gelu_erf(s1);
        #pragma unroll
        for (int f = 0; f < 8; f++) op[f] += s1 * sW2[j * 8 + f];
    }
    float hvh[4];
    #pragma unroll
    for (int fi = 0; fi < 4; fi++) {
        int f = fh * 4 + fi;
        float x = op[f] + __shfl_xor(op[f], 1, 64);
        x += __shfl_xor(x, 8, 64);
        hvh[fi] = gelu_erf(x * BN_SCALE * sg2[f] + sbt2[f]);
    }
    float hv[8];
    #pragma unroll
    for (int fi = 0; fi < 4; fi++) {
        hv[fh * 4 + fi] = hvh[fi];
        hv[(1 - fh) * 4 + fi] = __shfl_xor(hvh[fi], 1, 64);
    }

    float qp = 0.0f;
    #pragma unroll
    for (int jj = 0; jj < 2; jj++) {
        int j = jgroup * 2 + jj;
        float key = sbk[j];
        #pragma unroll
        for (int i2 = 0; i2 < 8; i2++) key += hv[i2] * sWk[i2 * 8 + j];
        qp += key * sWq[j];
    }
    float q = qp + __shfl_xor(qp, 1, 64);
    q += __shfl_xor(q, 8, 64);
    float w = sigmoidf_(q);
    if (fh == 0 && half == 0) w_out[(size_t)b * NGENES + g] = w;

    float contrib[4];
    #pragma unroll
    for (int fi = 0; fi < 4; fi++) {
        int f = fh * 4 + fi;
        float v = sbv[f];
        #pragma unroll
        for (int i2 = 0; i2 < 8; i2++) v += hv[i2] * sWv[i2 * 8 + f];
        contrib[fi] = (half == 0) ? v * w : 0.0f;
    }
    #pragma unroll
    for (int fi = 0; fi < 4; fi++) {
        contrib[fi] += __shfl_xor(contrib[fi], 8, 64);
        contrib[fi] += __shfl_xor(contrib[fi], 16, 64);
        contrib[fi] += __shfl_xor(contrib[fi], 32, 64);
    }
    int wave = t >> 6, lane = t & 63;
    if (lane < 8) {
        #pragma unroll
        for (int fi = 0; fi < 4; fi++)
            sRed[wave][lane >> 1][(lane & 1) * 4 + fi] = contrib[fi];
    }
    __syncthreads();
    if (t < 32) {
        int bl = t >> 3, f = t & 7;
        float sm = sRed[0][bl][f] + sRed[1][bl][f] + sRed[2][bl][f] + sRed[3][bl][f];
        partial[(size_t)blockIdx.x * 32 + bl * 8 + f] = sm;
    }
}

// ---------------------------------------------------------------------------
// kE: fused reduce (16 waves x 8 bf, lane-mapping bit-identical to k_reduce)
//     + head MLP (thread-mapping bit-identical to k_head). One block, 1024 thr.
__global__ __launch_bounds__(1024) void kE_finish(const float* __restrict__ partial,
                                                  const float* __restrict__ Wp1, const float* __restrict__ bp1,
                                                  const float* __restrict__ gp1, const float* __restrict__ btp1,
                                                  const float* __restrict__ Wp2, const float* __restrict__ bp2,
                                                  const float* __restrict__ gp2, const float* __restrict__ btp2,
                                                  const float* __restrict__ Wp3, const float* __restrict__ bp3,
                                                  float* __restrict__ preds) {
    __shared__ float sgh[128];
    __shared__ float z1[16 * 64];
    __shared__ float z2[16 * 16];
    int t = threadIdx.x;
    int wv = t >> 6, ln = t & 63;
    #pragma unroll
    for (int bfi = 0; bfi < 8; bfi++) {
        int bf = wv * 8 + bfi;               // 16 waves x 8 = 128 outputs
        int b = bf >> 3, f = bf & 7;
        int c = b >> 2, bl = b & 3;
        float s = 0.0f;
        for (int j = ln; j < NBLK2 / 4; j += 64)
            s += partial[(size_t)(c + 4 * j) * 32 + bl * 8 + f];
        #pragma unroll
        for (int m = 1; m < 64; m <<= 1) s += __shfl_xor(s, m, 64);
        if (ln == 0) sgh[bf] = s;
    }
    __syncthreads();
    {
        int b = t >> 6, j = t & 63;
        float s = bp1[j];
        #pragma unroll
        for (int k = 0; k < 8; k++) s += sgh[b * 8 + k] * Wp1[k * 64 + j];
        s = s * BN_SCALE * gp1[j] + btp1[j];
        z1[b * 64 + j] = gelu_erf(s);
    }
    __syncthreads();
    if (t < 256) {
        int b = t >> 4, j = t & 15;
        float s = bp2[j];
        for (int k = 0; k < 64; k++) s += z1[b * 64 + k] * Wp2[k * 16 + j];
        s = s * BN_SCALE * gp2[j] + btp2[j];
        z2[b * 16 + j] = gelu_erf(s);
    }
    __syncthreads();
    if (t < 16) {
        float s = bp3[0];
        #pragma unroll
        for (int k = 0; k < 16; k++) s += z2[t * 16 + k] * Wp3[k];
        preds[t] = s;
    }
}

// ---------------------------------------------------------------------------
extern "C" void kernel_launch(void* const* d_in, const int* in_sizes, int n_in,
                              void* d_out, int out_size, void* d_ws, size_t ws_size,
                              hipStream_t stream) {
    const float* snp          = (const float*)d_in[0];
    const int*   snp_ids      = (const int*)  d_in[1];
    const int*   gene_of_node = (const int*)  d_in[2];
    const int*   edge_src     = (const int*)  d_in[3];
    const int*   edge_dst     = (const int*)  d_in[4];
    const float* filters      = (const float*)d_in[5];
    const float* eps          = (const float*)d_in[6];
    const float* W1  = (const float*)d_in[7];
    const float* b1  = (const float*)d_in[8];
    const float* g1  = (const float*)d_in[9];
    const float* bt1 = (const float*)d_in[10];
    const float* W2  = (const float*)d_in[11];
    const float* b2  = (const float*)d_in[12];
    const float* g2  = (const float*)d_in[13];
    const float* bt2 = (const float*)d_in[14];
    const float* Wk  = (const float*)d_in[15];
    const float* bk  = (const float*)d_in[16];
    const float* Wq  = (const float*)d_in[17];
    const float* Wv  = (const float*)d_in[18];
    const float* bv  = (const float*)d_in[19];
    const float* Wp1 = (const float*)d_in[20];
    const float* bp1 = (const float*)d_in[21];
    const float* gp1 = (const float*)d_in[22];
    const float* btp1= (const float*)d_in[23];
    const float* Wp2 = (const float*)d_in[24];
    const float* bp2 = (const float*)d_in[25];
    const float* gp2 = (const float*)d_in[26];
    const float* btp2= (const float*)d_in[27];
    const float* Wp3 = (const float*)d_in[28];
    const float* bp3 = (const float*)d_in[29];

    float* out        = (float*)d_out;
    float* out_preds  = out;
    float* out_filt   = out + 16;
    float* out_w      = out + 16 + NFILT * NSNPS;

    // ---- workspace layout
    char* ws = (char*)d_ws;
    size_t off = 0;
    u16* nodeRow = (u16*)(ws + off); off += (size_t)NSNPS * 64;                  // 32 MB
    u16* h0   = (u16*)(ws + off); off += (size_t)NGENES * 128 * 2;               // 5.12 MB
    u16* h1   = (u16*)(ws + off); off += (size_t)NGENES * 128 * 2;               // 5.12 MB
    int* node_off = (int*)(ws + off); off += ((NGENES + 1) * 4 + 255) / 256 * 256;
    int* csr_off  = (int*)(ws + off); off += ((NGENES + 1) * 4 + 255) / 256 * 256;
    int* cursor   = (int*)(ws + off); off += (NGENES * 4 + 255) / 256 * 256;
    int* csr_src  = (int*)(ws + off); off += (size_t)NEDGES * 4;
    float* partial= (float*)(ws + off); off += (size_t)NBLK2 * 32 * 4;           // 640 KB

    // 1. fused prep: node rows + out_filt + node_off + ILP degscan (csr_off/cursor)
    kA_prep<<<KA_NA + KA_NB + 1, 256, 0, stream>>>(
        snp, filters, gene_of_node, edge_dst, nodeRow, out_filt, node_off, csr_off, cursor);
    // 2. snp->gene gather (long pole first) + edge scatter
    kB_gather<<<NGENES + KB_SCAT, 256, 0, stream>>>(
        nodeRow, snp_ids, node_off, edge_src, edge_dst, cursor, csr_src, h0);
    // 3. GIN layer 1
    kC_gin1<<<NBLK2, 256, 0, stream>>>(h0, h1, csr_off, csr_src, eps + 0,
                                       W1 + 0 * 128, b1 + 0 * 16, g1 + 0 * 16, bt1 + 0 * 16,
                                       W2 + 0 * 128, b2 + 0 * 8, g2 + 0 * 8, bt2 + 0 * 8);
    // 4. GIN layer 2 + readout partials
    kD_gin2<<<NBLK2, 256, 0, stream>>>(h1, csr_off, csr_src, eps + 1,
                                       W1 + 1 * 128, b1 + 1 * 16, g1 + 1 * 16, bt1 + 1 * 16,
                                       W2 + 1 * 128, b2 + 1 * 8, g2 + 1 * 8, bt2 + 1 * 8,
                                       Wk, bk, Wq, Wv, bv, out_w, partial);
    // 5. fused reduce + head
    kE_finish<<<1, 1024, 0, stream>>>(partial, Wp1, bp1, gp1, btp1,
                                      Wp2, bp2, gp2, btp2, Wp3, bp3, out_preds);
}

// Round 5
// 271.102 us; speedup vs baseline: 5.3469x; 1.4968x over previous
//
#include <hip/hip_runtime.h>
#include <math.h>

#define NSNPS  500000
#define NGENES 20000
#define NNODES 600000
#define NEDGES 320000
#define BB     16
#define NFILT  8
#define NBLK2  5000   // gin grid = (NGENES/16)*4
#define MAXDEG 64     // binomial(320K,1/20K): mean 16, max~34; P(>64) ~ e^-40

// rsqrt(1 + 1e-5)
#define BN_SCALE 0.99999500003749968f

typedef unsigned short u16;

__device__ __forceinline__ float gelu_erf(float x) {
    return 0.5f * x * (1.0f + erff(x * 0.70710678118654752f));
}
__device__ __forceinline__ float sigmoidf_(float x) {
    return 1.0f / (1.0f + expf(-x));
}
// fp32 -> bf16 round-to-nearest-even
__device__ __forceinline__ u16 f2bf(float x) {
    unsigned u = __float_as_uint(x);
    u += 0x7fffu + ((u >> 16) & 1u);
    return (u16)(u >> 16);
}
__device__ __forceinline__ float bf1(u16 v)      { return __uint_as_float(((unsigned)v) << 16); }
__device__ __forceinline__ float bflo(unsigned v){ return __uint_as_float(v << 16); }
__device__ __forceinline__ float bfhi(unsigned v){ return __uint_as_float(v & 0xffff0000u); }
__device__ __forceinline__ unsigned pack2(float a, float b) {
    return (unsigned)f2bf(a) | ((unsigned)f2bf(b) << 16);
}

// ---------------------------------------------------------------------------
// kA: fused prep — NO LDS, pure streaming (high occupancy).
//   blocks [0, KA_NA)           : 64B nodeRow (snp bf16 x16 | filt bf16 x8) + out_filt copy
//   blocks [KA_NA, KA_NA+KA_NB) : node_off binary search + cursor init (g*64) + g_h4 zero
#define KA_NA 1954   // ceil(NSNPS/256)
#define KA_NB 79     // ceil((NGENES+1)/256)
__global__ __launch_bounds__(256) void kA_prep(const float* __restrict__ snp,
                                               const float* __restrict__ filters,
                                               const int* __restrict__ gene_of_node,
                                               u16* __restrict__ nodeRow,
                                               float* __restrict__ out_filt,
                                               int* __restrict__ node_off,
                                               int* __restrict__ cursor,
                                               float* __restrict__ g_h4) {
    int bid = blockIdx.x;
    int t = threadIdx.x;

    if (bid < KA_NA) {
        int n = bid * 256 + t;
        if (n < NSNPS) {
            float f0 = filters[0 * NSNPS + n], f1 = filters[1 * NSNPS + n];
            float f2 = filters[2 * NSNPS + n], f3 = filters[3 * NSNPS + n];
            float f4 = filters[4 * NSNPS + n], f5 = filters[5 * NSNPS + n];
            float f6 = filters[6 * NSNPS + n], f7 = filters[7 * NSNPS + n];
            out_filt[0 * NSNPS + n] = f0; out_filt[1 * NSNPS + n] = f1;
            out_filt[2 * NSNPS + n] = f2; out_filt[3 * NSNPS + n] = f3;
            out_filt[4 * NSNPS + n] = f4; out_filt[5 * NSNPS + n] = f5;
            out_filt[6 * NSNPS + n] = f6; out_filt[7 * NSNPS + n] = f7;
            uint4 r0, r1, r2;
            r0.x = pack2(snp[0 * (size_t)NSNPS + n],  snp[1 * (size_t)NSNPS + n]);
            r0.y = pack2(snp[2 * (size_t)NSNPS + n],  snp[3 * (size_t)NSNPS + n]);
            r0.z = pack2(snp[4 * (size_t)NSNPS + n],  snp[5 * (size_t)NSNPS + n]);
            r0.w = pack2(snp[6 * (size_t)NSNPS + n],  snp[7 * (size_t)NSNPS + n]);
            r1.x = pack2(snp[8 * (size_t)NSNPS + n],  snp[9 * (size_t)NSNPS + n]);
            r1.y = pack2(snp[10 * (size_t)NSNPS + n], snp[11 * (size_t)NSNPS + n]);
            r1.z = pack2(snp[12 * (size_t)NSNPS + n], snp[13 * (size_t)NSNPS + n]);
            r1.w = pack2(snp[14 * (size_t)NSNPS + n], snp[15 * (size_t)NSNPS + n]);
            r2.x = pack2(f0, f1); r2.y = pack2(f2, f3);
            r2.z = pack2(f4, f5); r2.w = pack2(f6, f7);
            uint4* dst = (uint4*)(nodeRow + (size_t)n * 32);
            dst[0] = r0; dst[1] = r1; dst[2] = r2;   // 16B pad left unwritten
        }
        return;
    }
    int g = (bid - KA_NA) * 256 + t;
    if (g <= NGENES) {
        int lo = 0, hi = NNODES;
        while (lo < hi) {
            int mid = (lo + hi) >> 1;
            if (gene_of_node[mid] < g) lo = mid + 1; else hi = mid;
        }
        node_off[g] = lo;
    }
    if (g < NGENES) cursor[g] = g * MAXDEG;   // bump-allocator base
    if (g < 512)    g_h4[g] = 0.0f;           // 4 shards x 128
}

// ---------------------------------------------------------------------------
// kB: snp->gene gather (blocks [0, NGENES)) + bump-CSR edge scatter (last 1250).
#define KB_SCAT 1250
__global__ __launch_bounds__(256) void kB_gather(const u16* __restrict__ nodeRow,
                                                 const int* __restrict__ snp_ids,
                                                 const int* __restrict__ node_off,
                                                 const int* __restrict__ edge_src,
                                                 const int* __restrict__ edge_dst,
                                                 int* __restrict__ cursor,
                                                 int* __restrict__ csr_src,
                                                 u16* __restrict__ h_bf) {
    int bid = blockIdx.x;
    int t = threadIdx.x;
    if (bid >= NGENES) {
        int e = (bid - NGENES) * 256 + t;
        if (e < NEDGES) {
            int dst = edge_dst[e];
            int p = atomicAdd(&cursor[dst], 1);
            if (p < dst * MAXDEG + MAXDEG)    // overflow guard (never taken statistically)
                csr_src[p] = edge_src[e];
        }
        return;
    }
    __shared__ float sZ[4][128];
    int g = bid;
    int wave = t >> 6, lane = t & 63;
    int sub = (wave << 2) + (lane >> 4);     // 0..15
    int b = lane & 15;
    int s = node_off[g], e = node_off[g + 1];

    float acc[8];
    #pragma unroll
    for (int f = 0; f < 8; f++) acc[f] = 0.0f;

    int i = s + sub;
    for (; i + 16 < e; i += 32) {
        int id0 = snp_ids[i];
        int id1 = snp_ids[i + 16];
        const u16* r0 = nodeRow + (size_t)id0 * 32;
        const u16* r1 = nodeRow + (size_t)id1 * 32;
        float v0 = bf1(r0[b]);
        float v1 = bf1(r1[b]);
        uint4 F0 = *(const uint4*)(r0 + 16);
        uint4 F1 = *(const uint4*)(r1 + 16);
        acc[0] += v0 * bflo(F0.x) + v1 * bflo(F1.x);
        acc[1] += v0 * bfhi(F0.x) + v1 * bfhi(F1.x);
        acc[2] += v0 * bflo(F0.y) + v1 * bflo(F1.y);
        acc[3] += v0 * bfhi(F0.y) + v1 * bfhi(F1.y);
        acc[4] += v0 * bflo(F0.z) + v1 * bflo(F1.z);
        acc[5] += v0 * bfhi(F0.z) + v1 * bfhi(F1.z);
        acc[6] += v0 * bflo(F0.w) + v1 * bflo(F1.w);
        acc[7] += v0 * bfhi(F0.w) + v1 * bfhi(F1.w);
    }
    if (i < e) {
        int id0 = snp_ids[i];
        const u16* r0 = nodeRow + (size_t)id0 * 32;
        float v0 = bf1(r0[b]);
        uint4 F0 = *(const uint4*)(r0 + 16);
        acc[0] += v0 * bflo(F0.x); acc[1] += v0 * bfhi(F0.x);
        acc[2] += v0 * bflo(F0.y); acc[3] += v0 * bfhi(F0.y);
        acc[4] += v0 * bflo(F0.z); acc[5] += v0 * bfhi(F0.z);
        acc[6] += v0 * bflo(F0.w); acc[7] += v0 * bfhi(F0.w);
    }
    #pragma unroll
    for (int f = 0; f < 8; f++) {
        acc[f] += __shfl_xor(acc[f], 16, 64);
        acc[f] += __shfl_xor(acc[f], 32, 64);
    }
    if (lane < 16) {   // lane == b
        float* dst = &sZ[wave][lane * 8];
        *(float4*)(dst)     = make_float4(acc[0], acc[1], acc[2], acc[3]);
        *(float4*)(dst + 4) = make_float4(acc[4], acc[5], acc[6], acc[7]);
    }
    __syncthreads();
    if (t < 128) {
        float val = sZ[0][t] + sZ[1][t] + sZ[2][t] + sZ[3][t];
        h_bf[(size_t)g * 128 + t] = f2bf(val);
    }
}

// ---------------------------------------------------------------------------
// kC: GIN layer 1 (bump-CSR: s = g*64, e = min(cursor[g], s+64)).
__global__ __launch_bounds__(256) void kC_gin1(const u16* __restrict__ hin,
                                               u16* __restrict__ hout,
                                               const int* __restrict__ cursor,
                                               const int* __restrict__ csr_src,
                                               const float* __restrict__ eps_l,
                                               const float* __restrict__ W1,
                                               const float* __restrict__ b1,
                                               const float* __restrict__ g1,
                                               const float* __restrict__ bt1,
                                               const float* __restrict__ W2,
                                               const float* __restrict__ b2,
                                               const float* __restrict__ g2,
                                               const float* __restrict__ bt2) {
    __shared__ float sW1[128], sb1[16], sg1[16], sbt1[16];
    __shared__ float sW2[128], sb2[8], sg2[8], sbt2[8];
    int t = threadIdx.x;
    if (t < 128) { sW1[t] = W1[t]; sW2[t] = W2[t]; }
    if (t < 16)  { sb1[t] = b1[t]; sg1[t] = g1[t]; sbt1[t] = bt1[t]; }
    if (t < 8)   { sb2[t] = b2[t]; sg2[t] = g2[t]; sbt2[t] = bt2[t]; }

    int chunk = blockIdx.x & 3;
    int g = (blockIdx.x >> 2) * 16 + (t >> 4);
    int u = t & 15;
    int half = u >> 3;
    int colpos = u & 7;
    int fh = colpos & 1;
    int jgroup = half * 2 + fh;
    int col = chunk * 32 + colpos * 4;
    const u16* __restrict__ hc = hin + col;
    float epsv = 1.0f + eps_l[0];

    float a0, a1, a2, a3;
    if (half == 0) {
        uint2 su = *(const uint2*)(hc + (size_t)g * 128);
        a0 = bflo(su.x) * epsv; a1 = bfhi(su.x) * epsv;
        a2 = bflo(su.y) * epsv; a3 = bfhi(su.y) * epsv;
    } else {
        a0 = a1 = a2 = a3 = 0.0f;
    }

    int s = g * MAXDEG;
    int e = cursor[g];
    e = (e < s + MAXDEG) ? e : (s + MAXDEG);
    int k = s + half;
    for (; k + 14 < e; k += 16) {
        int i0 = csr_src[k],      i1 = csr_src[k + 2];
        int i2 = csr_src[k + 4],  i3 = csr_src[k + 6];
        int i4 = csr_src[k + 8],  i5 = csr_src[k + 10];
        int i6 = csr_src[k + 12], i7 = csr_src[k + 14];
        uint2 v0 = *(const uint2*)(hc + (size_t)i0 * 128);
        uint2 v1 = *(const uint2*)(hc + (size_t)i1 * 128);
        uint2 v2 = *(const uint2*)(hc + (size_t)i2 * 128);
        uint2 v3 = *(const uint2*)(hc + (size_t)i3 * 128);
        uint2 v4 = *(const uint2*)(hc + (size_t)i4 * 128);
        uint2 v5 = *(const uint2*)(hc + (size_t)i5 * 128);
        uint2 v6 = *(const uint2*)(hc + (size_t)i6 * 128);
        uint2 v7 = *(const uint2*)(hc + (size_t)i7 * 128);
        a0 += ((bflo(v0.x) + bflo(v1.x)) + (bflo(v2.x) + bflo(v3.x)))
            + ((bflo(v4.x) + bflo(v5.x)) + (bflo(v6.x) + bflo(v7.x)));
        a1 += ((bfhi(v0.x) + bfhi(v1.x)) + (bfhi(v2.x) + bfhi(v3.x)))
            + ((bfhi(v4.x) + bfhi(v5.x)) + (bfhi(v6.x) + bfhi(v7.x)));
        a2 += ((bflo(v0.y) + bflo(v1.y)) + (bflo(v2.y) + bflo(v3.y)))
            + ((bflo(v4.y) + bflo(v5.y)) + (bflo(v6.y) + bflo(v7.y)));
        a3 += ((bfhi(v0.y) + bfhi(v1.y)) + (bfhi(v2.y) + bfhi(v3.y)))
            + ((bfhi(v4.y) + bfhi(v5.y)) + (bfhi(v6.y) + bfhi(v7.y)));
    }
    for (; k < e; k += 2) {
        int i0 = csr_src[k];
        uint2 v0 = *(const uint2*)(hc + (size_t)i0 * 128);
        a0 += bflo(v0.x); a1 += bfhi(v0.x);
        a2 += bflo(v0.y); a3 += bfhi(v0.y);
    }
    __syncthreads();

    a0 += __shfl_xor(a0, 8, 64);
    a1 += __shfl_xor(a1, 8, 64);
    a2 += __shfl_xor(a2, 8, 64);
    a3 += __shfl_xor(a3, 8, 64);
    float p0 = __shfl_xor(a0, 1, 64);
    float p1 = __shfl_xor(a1, 1, 64);
    float p2 = __shfl_xor(a2, 1, 64);
    float p3 = __shfl_xor(a3, 1, 64);
    float z[8];
    z[fh * 4 + 0] = a0; z[fh * 4 + 1] = a1; z[fh * 4 + 2] = a2; z[fh * 4 + 3] = a3;
    z[(1 - fh) * 4 + 0] = p0; z[(1 - fh) * 4 + 1] = p1;
    z[(1 - fh) * 4 + 2] = p2; z[(1 - fh) * 4 + 3] = p3;

    float op[8];
    #pragma unroll
    for (int f = 0; f < 8; f++) op[f] = (jgroup == 0) ? sb2[f] : 0.0f;
    #pragma unroll
    for (int jj = 0; jj < 4; jj++) {
        int j = jgroup * 4 + jj;
        float s1 = sb1[j];
        #pragma unroll
        for (int i2 = 0; i2 < 8; i2++) s1 += z[i2] * sW1[i2 * 16 + j];
        s1 = s1 * BN_SCALE * sg1[j] + sbt1[j];
        s1 = gelu_erf(s1);
        #pragma unroll
        for (int f = 0; f < 8; f++) op[f] += s1 * sW2[j * 8 + f];
    }
    float r[4];
    #pragma unroll
    for (int fi = 0; fi < 4; fi++) {
        int f = fh * 4 + fi;
        float x = op[f] + __shfl_xor(op[f], 1, 64);
        x += __shfl_xor(x, 8, 64);
        r[fi] = gelu_erf(x * BN_SCALE * sg2[f] + sbt2[f]);
    }
    if (half == 0) {
        uint2 ou;
        ou.x = pack2(r[0], r[1]); ou.y = pack2(r[2], r[3]);
        *(uint2*)(hout + (size_t)g * 128 + col) = ou;
    }
}

// ---------------------------------------------------------------------------
// kD: GIN layer 2 + attentive readout -> sharded global atomic g_h4[4][128].
__global__ __launch_bounds__(256) void kD_gin2(const u16* __restrict__ hin,
                                               const int* __restrict__ cursor,
                                               const int* __restrict__ csr_src,
                                               const float* __restrict__ eps_l,
                                               const float* __restrict__ W1,
                                               const float* __restrict__ b1,
                                               const float* __restrict__ g1,
                                               const float* __restrict__ bt1,
                                               const float* __restrict__ W2,
                                               const float* __restrict__ b2,
                                               const float* __restrict__ g2,
                                               const float* __restrict__ bt2,
                                               const float* __restrict__ Wk,
                                               const float* __restrict__ bk,
                                               const float* __restrict__ Wq,
                                               const float* __restrict__ Wv,
                                               const float* __restrict__ bv,
                                               float* __restrict__ w_out,
                                               float* __restrict__ g_h4) {
    __shared__ float sW1[128], sb1[16], sg1[16], sbt1[16];
    __shared__ float sW2[128], sb2[8], sg2[8], sbt2[8];
    __shared__ float sWk[64], sWv[64], sbk[8], sbv[8], sWq[8];
    __shared__ float sRed[4][4][8];
    int t = threadIdx.x;
    if (t < 128) { sW1[t] = W1[t]; sW2[t] = W2[t]; }
    if (t < 64)  { sWk[t] = Wk[t]; sWv[t] = Wv[t]; }
    if (t < 16)  { sb1[t] = b1[t]; sg1[t] = g1[t]; sbt1[t] = bt1[t]; }
    if (t < 8)   { sb2[t] = b2[t]; sg2[t] = g2[t]; sbt2[t] = bt2[t];
                   sbk[t] = bk[t]; sbv[t] = bv[t]; sWq[t] = Wq[t]; }

    int chunk = blockIdx.x & 3;
    int g = (blockIdx.x >> 2) * 16 + (t >> 4);
    int u = t & 15;
    int half = u >> 3;
    int colpos = u & 7;
    int fh = colpos & 1;
    int jgroup = half * 2 + fh;
    int b = chunk * 4 + (colpos >> 1);
    int col = chunk * 32 + colpos * 4;
    const u16* __restrict__ hc = hin + col;
    float epsv = 1.0f + eps_l[0];

    float a0, a1, a2, a3;
    if (half == 0) {
        uint2 su = *(const uint2*)(hc + (size_t)g * 128);
        a0 = bflo(su.x) * epsv; a1 = bfhi(su.x) * epsv;
        a2 = bflo(su.y) * epsv; a3 = bfhi(su.y) * epsv;
    } else {
        a0 = a1 = a2 = a3 = 0.0f;
    }

    int s = g * MAXDEG;
    int e = cursor[g];
    e = (e < s + MAXDEG) ? e : (s + MAXDEG);
    int k = s + half;
    for (; k + 14 < e; k += 16) {
        int i0 = csr_src[k],      i1 = csr_src[k + 2];
        int i2 = csr_src[k + 4],  i3 = csr_src[k + 6];
        int i4 = csr_src[k + 8],  i5 = csr_src[k + 10];
        int i6 = csr_src[k + 12], i7 = csr_src[k + 14];
        uint2 v0 = *(const uint2*)(hc + (size_t)i0 * 128);
        uint2 v1 = *(const uint2*)(hc + (size_t)i1 * 128);
        uint2 v2 = *(const uint2*)(hc + (size_t)i2 * 128);
        uint2 v3 = *(const uint2*)(hc + (size_t)i3 * 128);
        uint2 v4 = *(const uint2*)(hc + (size_t)i4 * 128);
        uint2 v5 = *(const uint2*)(hc + (size_t)i5 * 128);
        uint2 v6 = *(const uint2*)(hc + (size_t)i6 * 128);
        uint2 v7 = *(const uint2*)(hc + (size_t)i7 * 128);
        a0 += ((bflo(v0.x) + bflo(v1.x)) + (bflo(v2.x) + bflo(v3.x)))
            + ((bflo(v4.x) + bflo(v5.x)) + (bflo(v6.x) + bflo(v7.x)));
        a1 += ((bfhi(v0.x) + bfhi(v1.x)) + (bfhi(v2.x) + bfhi(v3.x)))
            + ((bfhi(v4.x) + bfhi(v5.x)) + (bfhi(v6.x) + bfhi(v7.x)));
        a2 += ((bflo(v0.y) + bflo(v1.y)) + (bflo(v2.y) + bflo(v3.y)))
            + ((bflo(v4.y) + bflo(v5.y)) + (bflo(v6.y) + bflo(v7.y)));
        a3 += ((bfhi(v0.y) + bfhi(v1.y)) + (bfhi(v2.y) + bfhi(v3.y)))
            + ((bfhi(v4.y) + bfhi(v5.y)) + (bfhi(v6.y) + bfhi(v7.y)));
    }
    for (; k < e; k += 2) {
        int i0 = csr_src[k];
        uint2 v0 = *(const uint2*)(hc + (size_t)i0 * 128);
        a0 += bflo(v0.x); a1 += bfhi(v0.x);
        a2 += bflo(v0.y); a3 += bfhi(v0.y);
    }
    __syncthreads();

    a0 += __shfl_xor(a0, 8, 64);
    a1 += __shfl_xor(a1, 8, 64);
    a2 += __shfl_xor(a2, 8, 64);
    a3 += __shfl_xor(a3, 8, 64);
    float p0 = __shfl_xor(a0, 1, 64);
    float p1 = __shfl_xor(a1, 1, 64);
    float p2 = __shfl_xor(a2, 1, 64);
    float p3 = __shfl_xor(a3, 1, 64);
    float z[8];
    z[fh * 4 + 0] = a0; z[fh * 4 + 1] = a1; z[fh * 4 + 2] = a2; z[fh * 4 + 3] = a3;
    z[(1 - fh) * 4 + 0] = p0; z[(1 - fh) * 4 + 1] = p1;
    z[(1 - fh) * 4 + 2] = p2; z[(1 - fh) * 4 + 3] = p3;

    float op[8];
    #pragma unroll
    for (int f = 0; f < 8; f++) op[f] = (jgroup == 0) ? sb2[f] : 0.0f;
    #pragma unroll
    for (int jj = 0; jj < 4; jj++) {
        int j = jgroup * 4 + jj;
        float s1 = sb1[j];
        #pragma unroll
        for (int i2 = 0; i2 < 8; i2++) s1 += z[i2] * sW1[i2 * 16 + j];
        s1 = s1 * BN_SCALE * sg1[j] + sbt1[j];
        s1 = gelu_erf(s1);
        #pragma unroll
        for (int f = 0; f < 8; f++) op[f] += s1 * sW2[j * 8 + f];
    }
    float hvh[4];
    #pragma unroll
    for (int fi = 0; fi < 4; fi++) {
        int f = fh * 4 + fi;
        float x = op[f] + __shfl_xor(op[f], 1, 64);
        x += __shfl_xor(x, 8, 64);
        hvh[fi] = gelu_erf(x * BN_SCALE * sg2[f] + sbt2[f]);
    }
    float hv[8];
    #pragma unroll
    for (int fi = 0; fi < 4; fi++) {
        hv[fh * 4 + fi] = hvh[fi];
        hv[(1 - fh) * 4 + fi] = __shfl_xor(hvh[fi], 1, 64);
    }

    float qp = 0.0f;
    #pragma unroll
    for (int jj = 0; jj < 2; jj++) {
        int j = jgroup * 2 + jj;
        float key = sbk[j];
        #pragma unroll
        for (int i2 = 0; i2 < 8; i2++) key += hv[i2] * sWk[i2 * 8 + j];
        qp += key * sWq[j];
    }
    float q = qp + __shfl_xor(qp, 1, 64);
    q += __shfl_xor(q, 8, 64);
    float w = sigmoidf_(q);
    if (fh == 0 && half == 0) w_out[(size_t)b * NGENES + g] = w;

    float contrib[4];
    #pragma unroll
    for (int fi = 0; fi < 4; fi++) {
        int f = fh * 4 + fi;
        float v = sbv[f];
        #pragma unroll
        for (int i2 = 0; i2 < 8; i2++) v += hv[i2] * sWv[i2 * 8 + f];
        contrib[fi] = (half == 0) ? v * w : 0.0f;
    }
    #pragma unroll
    for (int fi = 0; fi < 4; fi++) {
        contrib[fi] += __shfl_xor(contrib[fi], 8, 64);
        contrib[fi] += __shfl_xor(contrib[fi], 16, 64);
        contrib[fi] += __shfl_xor(contrib[fi], 32, 64);
    }
    int wave = t >> 6, lane = t & 63;
    if (lane < 8) {
        #pragma unroll
        for (int fi = 0; fi < 4; fi++)
            sRed[wave][lane >> 1][(lane & 1) * 4 + fi] = contrib[fi];
    }
    __syncthreads();
    if (t < 32) {
        int bl = t >> 3, f = t & 7;
        float sm = sRed[0][bl][f] + sRed[1][bl][f] + sRed[2][bl][f] + sRed[3][bl][f];
        int shard = (blockIdx.x >> 2) & 3;
        atomicAdd(&g_h4[shard * 128 + (chunk * 4 + bl) * 8 + f], sm);
    }
}

// ---------------------------------------------------------------------------
// kE: head MLP only (reads g_h4 shards; thread-mapping identical to k_head).
__global__ __launch_bounds__(1024) void kE_head(const float* __restrict__ g_h4,
                                                const float* __restrict__ Wp1, const float* __restrict__ bp1,
                                                const float* __restrict__ gp1, const float* __restrict__ btp1,
                                                const float* __restrict__ Wp2, const float* __restrict__ bp2,
                                                const float* __restrict__ gp2, const float* __restrict__ btp2,
                                                const float* __restrict__ Wp3, const float* __restrict__ bp3,
                                                float* __restrict__ preds) {
    __shared__ float sgh[128];
    __shared__ float z1[16 * 64];
    __shared__ float z2[16 * 16];
    int t = threadIdx.x;
    if (t < 128) sgh[t] = (g_h4[t] + g_h4[128 + t]) + (g_h4[256 + t] + g_h4[384 + t]);
    __syncthreads();
    {
        int b = t >> 6, j = t & 63;
        float s = bp1[j];
        #pragma unroll
        for (int k = 0; k < 8; k++) s += sgh[b * 8 + k] * Wp1[k * 64 + j];
        s = s * BN_SCALE * gp1[j] + btp1[j];
        z1[b * 64 + j] = gelu_erf(s);
    }
    __syncthreads();
    if (t < 256) {
        int b = t >> 4, j = t & 15;
        float s = bp2[j];
        for (int k = 0; k < 64; k++) s += z1[b * 64 + k] * Wp2[k * 16 + j];
        s = s * BN_SCALE * gp2[j] + btp2[j];
        z2[b * 16 + j] = gelu_erf(s);
    }
    __syncthreads();
    if (t < 16) {
        float s = bp3[0];
        #pragma unroll
        for (int k = 0; k < 16; k++) s += z2[t * 16 + k] * Wp3[k];
        preds[t] = s;
    }
}

// ---------------------------------------------------------------------------
extern "C" void kernel_launch(void* const* d_in, const int* in_sizes, int n_in,
                              void* d_out, int out_size, void* d_ws, size_t ws_size,
                              hipStream_t stream) {
    const float* snp          = (const float*)d_in[0];
    const int*   snp_ids      = (const int*)  d_in[1];
    const int*   gene_of_node = (const int*)  d_in[2];
    const int*   edge_src     = (const int*)  d_in[3];
    const int*   edge_dst     = (const int*)  d_in[4];
    const float* filters      = (const float*)d_in[5];
    const float* eps          = (const float*)d_in[6];
    const float* W1  = (const float*)d_in[7];
    const float* b1  = (const float*)d_in[8];
    const float* g1  = (const float*)d_in[9];
    const float* bt1 = (const float*)d_in[10];
    const float* W2  = (const float*)d_in[11];
    const float* b2  = (const float*)d_in[12];
    const float* g2  = (const float*)d_in[13];
    const float* bt2 = (const float*)d_in[14];
    const float* Wk  = (const float*)d_in[15];
    const float* bk  = (const float*)d_in[16];
    const float* Wq  = (const float*)d_in[17];
    const float* Wv  = (const float*)d_in[18];
    const float* bv  = (const float*)d_in[19];
    const float* Wp1 = (const float*)d_in[20];
    const float* bp1 = (const float*)d_in[21];
    const float* gp1 = (const float*)d_in[22];
    const float* btp1= (const float*)d_in[23];
    const float* Wp2 = (const float*)d_in[24];
    const float* bp2 = (const float*)d_in[25];
    const float* gp2 = (const float*)d_in[26];
    const float* btp2= (const float*)d_in[27];
    const float* Wp3 = (const float*)d_in[28];
    const float* bp3 = (const float*)d_in[29];

    float* out        = (float*)d_out;
    float* out_preds  = out;
    float* out_filt   = out + 16;
    float* out_w      = out + 16 + NFILT * NSNPS;

    // ---- workspace layout
    char* ws = (char*)d_ws;
    size_t off = 0;
    u16* nodeRow = (u16*)(ws + off); off += (size_t)NSNPS * 64;                  // 32 MB
    u16* h0   = (u16*)(ws + off); off += (size_t)NGENES * 128 * 2;               // 5.12 MB
    u16* h1   = (u16*)(ws + off); off += (size_t)NGENES * 128 * 2;               // 5.12 MB
    int* node_off = (int*)(ws + off); off += ((NGENES + 1) * 4 + 255) / 256 * 256;
    int* cursor   = (int*)(ws + off); off += (NGENES * 4 + 255) / 256 * 256;
    int* csr_src  = (int*)(ws + off); off += (size_t)NGENES * MAXDEG * 4;        // 5.12 MB
    float* g_h4   = (float*)(ws + off); off += 4 * 128 * 4;

    // 1. prep: node rows + out_filt + node_off + cursor init + g_h4 zero (no LDS)
    kA_prep<<<KA_NA + KA_NB, 256, 0, stream>>>(
        snp, filters, gene_of_node, nodeRow, out_filt, node_off, cursor, g_h4);
    // 2. snp->gene gather + bump-CSR scatter
    kB_gather<<<NGENES + KB_SCAT, 256, 0, stream>>>(
        nodeRow, snp_ids, node_off, edge_src, edge_dst, cursor, csr_src, h0);
    // 3. GIN layer 1
    kC_gin1<<<NBLK2, 256, 0, stream>>>(h0, h1, cursor, csr_src, eps + 0,
                                       W1 + 0 * 128, b1 + 0 * 16, g1 + 0 * 16, bt1 + 0 * 16,
                                       W2 + 0 * 128, b2 + 0 * 8, g2 + 0 * 8, bt2 + 0 * 8);
    // 4. GIN layer 2 + readout (sharded atomic g_h4)
    kD_gin2<<<NBLK2, 256, 0, stream>>>(h1, cursor, csr_src, eps + 1,
                                       W1 + 1 * 128, b1 + 1 * 16, g1 + 1 * 16, bt1 + 1 * 16,
                                       W2 + 1 * 128, b2 + 1 * 8, g2 + 1 * 8, bt2 + 1 * 8,
                                       Wk, bk, Wq, Wv, bv, out_w, g_h4);
    // 5. head MLP
    kE_head<<<1, 1024, 0, stream>>>(g_h4, Wp1, bp1, gp1, btp1,
                                    Wp2, bp2, gp2, btp2, Wp3, bp3, out_preds);
}

// Round 6
// 261.834 us; speedup vs baseline: 5.5361x; 1.0354x over previous
//
#include <hip/hip_runtime.h>
#include <math.h>

#define NSNPS  500000
#define NGENES 20000
#define NNODES 600000
#define NEDGES 320000
#define BB     16
#define NFILT  8
#define NBLK2  5000   // gin grid = (NGENES/16)*4
#define MAXDEG 64     // binomial(320K,1/20K): mean 16, max~34; P(>64) ~ e^-40

// rsqrt(1 + 1e-5)
#define BN_SCALE 0.99999500003749968f

typedef unsigned short u16;

__device__ __forceinline__ float gelu_erf(float x) {
    return 0.5f * x * (1.0f + erff(x * 0.70710678118654752f));
}
__device__ __forceinline__ float sigmoidf_(float x) {
    return 1.0f / (1.0f + expf(-x));
}
// fp32 -> bf16 round-to-nearest-even
__device__ __forceinline__ u16 f2bf(float x) {
    unsigned u = __float_as_uint(x);
    u += 0x7fffu + ((u >> 16) & 1u);
    return (u16)(u >> 16);
}
__device__ __forceinline__ float bf1(u16 v)      { return __uint_as_float(((unsigned)v) << 16); }
__device__ __forceinline__ float bflo(unsigned v){ return __uint_as_float(v << 16); }
__device__ __forceinline__ float bfhi(unsigned v){ return __uint_as_float(v & 0xffff0000u); }
__device__ __forceinline__ unsigned pack2(float a, float b) {
    return (unsigned)f2bf(a) | ((unsigned)f2bf(b) << 16);
}

// ---------------------------------------------------------------------------
// kA: fused prep — NO LDS, pure streaming (high occupancy).
//   blocks [0, KA_NA)           : 64B nodeRow (snp bf16 x16 | filt bf16 x8) + out_filt copy
//   blocks [KA_NA, KA_NA+KA_NB) : node_off binary search + cursor init (g*64) + g_h8 zero
#define KA_NA 1954   // ceil(NSNPS/256)
#define KA_NB 79     // ceil((NGENES+1)/256)
__global__ __launch_bounds__(256) void kA_prep(const float* __restrict__ snp,
                                               const float* __restrict__ filters,
                                               const int* __restrict__ gene_of_node,
                                               u16* __restrict__ nodeRow,
                                               float* __restrict__ out_filt,
                                               int* __restrict__ node_off,
                                               int* __restrict__ cursor,
                                               float* __restrict__ g_h8) {
    int bid = blockIdx.x;
    int t = threadIdx.x;

    if (bid < KA_NA) {
        int n = bid * 256 + t;
        if (n < NSNPS) {
            float f0 = filters[0 * NSNPS + n], f1 = filters[1 * NSNPS + n];
            float f2 = filters[2 * NSNPS + n], f3 = filters[3 * NSNPS + n];
            float f4 = filters[4 * NSNPS + n], f5 = filters[5 * NSNPS + n];
            float f6 = filters[6 * NSNPS + n], f7 = filters[7 * NSNPS + n];
            out_filt[0 * NSNPS + n] = f0; out_filt[1 * NSNPS + n] = f1;
            out_filt[2 * NSNPS + n] = f2; out_filt[3 * NSNPS + n] = f3;
            out_filt[4 * NSNPS + n] = f4; out_filt[5 * NSNPS + n] = f5;
            out_filt[6 * NSNPS + n] = f6; out_filt[7 * NSNPS + n] = f7;
            uint4 r0, r1, r2;
            r0.x = pack2(snp[0 * (size_t)NSNPS + n],  snp[1 * (size_t)NSNPS + n]);
            r0.y = pack2(snp[2 * (size_t)NSNPS + n],  snp[3 * (size_t)NSNPS + n]);
            r0.z = pack2(snp[4 * (size_t)NSNPS + n],  snp[5 * (size_t)NSNPS + n]);
            r0.w = pack2(snp[6 * (size_t)NSNPS + n],  snp[7 * (size_t)NSNPS + n]);
            r1.x = pack2(snp[8 * (size_t)NSNPS + n],  snp[9 * (size_t)NSNPS + n]);
            r1.y = pack2(snp[10 * (size_t)NSNPS + n], snp[11 * (size_t)NSNPS + n]);
            r1.z = pack2(snp[12 * (size_t)NSNPS + n], snp[13 * (size_t)NSNPS + n]);
            r1.w = pack2(snp[14 * (size_t)NSNPS + n], snp[15 * (size_t)NSNPS + n]);
            r2.x = pack2(f0, f1); r2.y = pack2(f2, f3);
            r2.z = pack2(f4, f5); r2.w = pack2(f6, f7);
            uint4* dst = (uint4*)(nodeRow + (size_t)n * 32);
            dst[0] = r0; dst[1] = r1; dst[2] = r2;   // 16B pad left unwritten
        }
        return;
    }
    int g = (bid - KA_NA) * 256 + t;
    if (g <= NGENES) {
        int lo = 0, hi = NNODES;
        while (lo < hi) {
            int mid = (lo + hi) >> 1;
            if (gene_of_node[mid] < g) lo = mid + 1; else hi = mid;
        }
        node_off[g] = lo;
    }
    if (g < NGENES) cursor[g] = g * MAXDEG;   // bump-allocator base
    if (g < 1024)   g_h8[g] = 0.0f;           // 8 shards x 128
}

// ---------------------------------------------------------------------------
// kB: bump-CSR edge scatter FIRST (blocks [0,1250): no tail), then gather —
// one WAVE per gene, 4 genes/block, barrier-free, no LDS, 4-deep load ILP.
#define KB_SCAT 1250
#define KB_GATH 5000   // x4 genes/block = 20000 genes
__global__ __launch_bounds__(256) void kB_gather(const u16* __restrict__ nodeRow,
                                                 const int* __restrict__ snp_ids,
                                                 const int* __restrict__ node_off,
                                                 const int* __restrict__ edge_src,
                                                 const int* __restrict__ edge_dst,
                                                 int* __restrict__ cursor,
                                                 int* __restrict__ csr_src,
                                                 u16* __restrict__ h_bf) {
    int bid = blockIdx.x;
    int t = threadIdx.x;
    if (bid < KB_SCAT) {
        int e = bid * 256 + t;
        if (e < NEDGES) {
            int dst = edge_dst[e];
            int p = atomicAdd(&cursor[dst], 1);
            if (p < dst * MAXDEG + MAXDEG)    // overflow guard (never taken statistically)
                csr_src[p] = edge_src[e];
        }
        return;
    }
    int wave = t >> 6, lane = t & 63;
    int g = (bid - KB_SCAT) * 4 + wave;       // one gene per wave, independent
    int slot = lane >> 4;                     // 0..3
    int b = lane & 15;
    int s = node_off[g], e = node_off[g + 1];

    float acc[8];
    #pragma unroll
    for (int f = 0; f < 8; f++) acc[f] = 0.0f;

    int i = s + slot;
    for (; i + 12 < e; i += 16) {             // 4 rows in flight per lane
        int id0 = snp_ids[i];
        int id1 = snp_ids[i + 4];
        int id2 = snp_ids[i + 8];
        int id3 = snp_ids[i + 12];
        const u16* r0 = nodeRow + (size_t)id0 * 32;
        const u16* r1 = nodeRow + (size_t)id1 * 32;
        const u16* r2 = nodeRow + (size_t)id2 * 32;
        const u16* r3 = nodeRow + (size_t)id3 * 32;
        float v0 = bf1(r0[b]);
        float v1 = bf1(r1[b]);
        float v2 = bf1(r2[b]);
        float v3 = bf1(r3[b]);
        uint4 F0 = *(const uint4*)(r0 + 16);
        uint4 F1 = *(const uint4*)(r1 + 16);
        uint4 F2 = *(const uint4*)(r2 + 16);
        uint4 F3 = *(const uint4*)(r3 + 16);
        acc[0] += (v0 * bflo(F0.x) + v1 * bflo(F1.x)) + (v2 * bflo(F2.x) + v3 * bflo(F3.x));
        acc[1] += (v0 * bfhi(F0.x) + v1 * bfhi(F1.x)) + (v2 * bfhi(F2.x) + v3 * bfhi(F3.x));
        acc[2] += (v0 * bflo(F0.y) + v1 * bflo(F1.y)) + (v2 * bflo(F2.y) + v3 * bflo(F3.y));
        acc[3] += (v0 * bfhi(F0.y) + v1 * bfhi(F1.y)) + (v2 * bfhi(F2.y) + v3 * bfhi(F3.y));
        acc[4] += (v0 * bflo(F0.z) + v1 * bflo(F1.z)) + (v2 * bflo(F2.z) + v3 * bflo(F3.z));
        acc[5] += (v0 * bfhi(F0.z) + v1 * bfhi(F1.z)) + (v2 * bfhi(F2.z) + v3 * bfhi(F3.z));
        acc[6] += (v0 * bflo(F0.w) + v1 * bflo(F1.w)) + (v2 * bflo(F2.w) + v3 * bflo(F3.w));
        acc[7] += (v0 * bfhi(F0.w) + v1 * bfhi(F1.w)) + (v2 * bfhi(F2.w) + v3 * bfhi(F3.w));
    }
    for (; i + 4 < e; i += 8) {               // 2 rows in flight
        int id0 = snp_ids[i];
        int id1 = snp_ids[i + 4];
        const u16* r0 = nodeRow + (size_t)id0 * 32;
        const u16* r1 = nodeRow + (size_t)id1 * 32;
        float v0 = bf1(r0[b]);
        float v1 = bf1(r1[b]);
        uint4 F0 = *(const uint4*)(r0 + 16);
        uint4 F1 = *(const uint4*)(r1 + 16);
        acc[0] += v0 * bflo(F0.x) + v1 * bflo(F1.x);
        acc[1] += v0 * bfhi(F0.x) + v1 * bfhi(F1.x);
        acc[2] += v0 * bflo(F0.y) + v1 * bflo(F1.y);
        acc[3] += v0 * bfhi(F0.y) + v1 * bfhi(F1.y);
        acc[4] += v0 * bflo(F0.z) + v1 * bflo(F1.z);
        acc[5] += v0 * bfhi(F0.z) + v1 * bfhi(F1.z);
        acc[6] += v0 * bflo(F0.w) + v1 * bflo(F1.w);
        acc[7] += v0 * bfhi(F0.w) + v1 * bfhi(F1.w);
    }
    if (i < e) {
        int id0 = snp_ids[i];
        const u16* r0 = nodeRow + (size_t)id0 * 32;
        float v0 = bf1(r0[b]);
        uint4 F0 = *(const uint4*)(r0 + 16);
        acc[0] += v0 * bflo(F0.x); acc[1] += v0 * bfhi(F0.x);
        acc[2] += v0 * bflo(F0.y); acc[3] += v0 * bfhi(F0.y);
        acc[4] += v0 * bflo(F0.z); acc[5] += v0 * bfhi(F0.z);
        acc[6] += v0 * bflo(F0.w); acc[7] += v0 * bfhi(F0.w);
    }
    // combine the 4 slots (lane bits 4,5) — wave-local, no LDS, no barrier
    #pragma unroll
    for (int f = 0; f < 8; f++) {
        acc[f] += __shfl_xor(acc[f], 16, 64);
        acc[f] += __shfl_xor(acc[f], 32, 64);
    }
    if (lane < 16) {   // lane == b: pack own 8 f's, 16B store, 256B/gene coalesced
        uint4 o;
        o.x = pack2(acc[0], acc[1]); o.y = pack2(acc[2], acc[3]);
        o.z = pack2(acc[4], acc[5]); o.w = pack2(acc[6], acc[7]);
        *(uint4*)(h_bf + (size_t)g * 128 + lane * 8) = o;
    }
}

// ---------------------------------------------------------------------------
// kC: GIN layer 1 (bump-CSR: s = g*64, e = min(cursor[g], s+64)).
__global__ __launch_bounds__(256) void kC_gin1(const u16* __restrict__ hin,
                                               u16* __restrict__ hout,
                                               const int* __restrict__ cursor,
                                               const int* __restrict__ csr_src,
                                               const float* __restrict__ eps_l,
                                               const float* __restrict__ W1,
                                               const float* __restrict__ b1,
                                               const float* __restrict__ g1,
                                               const float* __restrict__ bt1,
                                               const float* __restrict__ W2,
                                               const float* __restrict__ b2,
                                               const float* __restrict__ g2,
                                               const float* __restrict__ bt2) {
    __shared__ float sW1[128], sb1[16], sg1[16], sbt1[16];
    __shared__ float sW2[128], sb2[8], sg2[8], sbt2[8];
    int t = threadIdx.x;
    if (t < 128) { sW1[t] = W1[t]; sW2[t] = W2[t]; }
    if (t < 16)  { sb1[t] = b1[t]; sg1[t] = g1[t]; sbt1[t] = bt1[t]; }
    if (t < 8)   { sb2[t] = b2[t]; sg2[t] = g2[t]; sbt2[t] = bt2[t]; }

    int chunk = blockIdx.x & 3;
    int g = (blockIdx.x >> 2) * 16 + (t >> 4);
    int u = t & 15;
    int half = u >> 3;
    int colpos = u & 7;
    int fh = colpos & 1;
    int jgroup = half * 2 + fh;
    int col = chunk * 32 + colpos * 4;
    const u16* __restrict__ hc = hin + col;
    float epsv = 1.0f + eps_l[0];

    float a0, a1, a2, a3;
    if (half == 0) {
        uint2 su = *(const uint2*)(hc + (size_t)g * 128);
        a0 = bflo(su.x) * epsv; a1 = bfhi(su.x) * epsv;
        a2 = bflo(su.y) * epsv; a3 = bfhi(su.y) * epsv;
    } else {
        a0 = a1 = a2 = a3 = 0.0f;
    }

    int s = g * MAXDEG;
    int e = cursor[g];
    e = (e < s + MAXDEG) ? e : (s + MAXDEG);
    int k = s + half;
    for (; k + 14 < e; k += 16) {
        int i0 = csr_src[k],      i1 = csr_src[k + 2];
        int i2 = csr_src[k + 4],  i3 = csr_src[k + 6];
        int i4 = csr_src[k + 8],  i5 = csr_src[k + 10];
        int i6 = csr_src[k + 12], i7 = csr_src[k + 14];
        uint2 v0 = *(const uint2*)(hc + (size_t)i0 * 128);
        uint2 v1 = *(const uint2*)(hc + (size_t)i1 * 128);
        uint2 v2 = *(const uint2*)(hc + (size_t)i2 * 128);
        uint2 v3 = *(const uint2*)(hc + (size_t)i3 * 128);
        uint2 v4 = *(const uint2*)(hc + (size_t)i4 * 128);
        uint2 v5 = *(const uint2*)(hc + (size_t)i5 * 128);
        uint2 v6 = *(const uint2*)(hc + (size_t)i6 * 128);
        uint2 v7 = *(const uint2*)(hc + (size_t)i7 * 128);
        a0 += ((bflo(v0.x) + bflo(v1.x)) + (bflo(v2.x) + bflo(v3.x)))
            + ((bflo(v4.x) + bflo(v5.x)) + (bflo(v6.x) + bflo(v7.x)));
        a1 += ((bfhi(v0.x) + bfhi(v1.x)) + (bfhi(v2.x) + bfhi(v3.x)))
            + ((bfhi(v4.x) + bfhi(v5.x)) + (bfhi(v6.x) + bfhi(v7.x)));
        a2 += ((bflo(v0.y) + bflo(v1.y)) + (bflo(v2.y) + bflo(v3.y)))
            + ((bflo(v4.y) + bflo(v5.y)) + (bflo(v6.y) + bflo(v7.y)));
        a3 += ((bfhi(v0.y) + bfhi(v1.y)) + (bfhi(v2.y) + bfhi(v3.y)))
            + ((bfhi(v4.y) + bfhi(v5.y)) + (bfhi(v6.y) + bfhi(v7.y)));
    }
    for (; k < e; k += 2) {
        int i0 = csr_src[k];
        uint2 v0 = *(const uint2*)(hc + (size_t)i0 * 128);
        a0 += bflo(v0.x); a1 += bfhi(v0.x);
        a2 += bflo(v0.y); a3 += bfhi(v0.y);
    }
    __syncthreads();

    a0 += __shfl_xor(a0, 8, 64);
    a1 += __shfl_xor(a1, 8, 64);
    a2 += __shfl_xor(a2, 8, 64);
    a3 += __shfl_xor(a3, 8, 64);
    float p0 = __shfl_xor(a0, 1, 64);
    float p1 = __shfl_xor(a1, 1, 64);
    float p2 = __shfl_xor(a2, 1, 64);
    float p3 = __shfl_xor(a3, 1, 64);
    float z[8];
    z[fh * 4 + 0] = a0; z[fh * 4 + 1] = a1; z[fh * 4 + 2] = a2; z[fh * 4 + 3] = a3;
    z[(1 - fh) * 4 + 0] = p0; z[(1 - fh) * 4 + 1] = p1;
    z[(1 - fh) * 4 + 2] = p2; z[(1 - fh) * 4 + 3] = p3;

    float op[8];
    #pragma unroll
    for (int f = 0; f < 8; f++) op[f] = (jgroup == 0) ? sb2[f] : 0.0f;
    #pragma unroll
    for (int jj = 0; jj < 4; jj++) {
        int j = jgroup * 4 + jj;
        float s1 = sb1[j];
        #pragma unroll
        for (int i2 = 0; i2 < 8; i2++) s1 += z[i2] * sW1[i2 * 16 + j];
        s1 = s1 * BN_SCALE * sg1[j] + sbt1[j];
        s1 = gelu_erf(s1);
        #pragma unroll
        for (int f = 0; f < 8; f++) op[f] += s1 * sW2[j * 8 + f];
    }
    float r[4];
    #pragma unroll
    for (int fi = 0; fi < 4; fi++) {
        int f = fh * 4 + fi;
        float x = op[f] + __shfl_xor(op[f], 1, 64);
        x += __shfl_xor(x, 8, 64);
        r[fi] = gelu_erf(x * BN_SCALE * sg2[f] + sbt2[f]);
    }
    if (half == 0) {
        uint2 ou;
        ou.x = pack2(r[0], r[1]); ou.y = pack2(r[2], r[3]);
        *(uint2*)(hout + (size_t)g * 128 + col) = ou;
    }
}

// ---------------------------------------------------------------------------
// kD: GIN layer 2 + attentive readout -> sharded global atomic g_h8[8][128].
__global__ __launch_bounds__(256) void kD_gin2(const u16* __restrict__ hin,
                                               const int* __restrict__ cursor,
                                               const int* __restrict__ csr_src,
                                               const float* __restrict__ eps_l,
                                               const float* __restrict__ W1,
                                               const float* __restrict__ b1,
                                               const float* __restrict__ g1,
                                               const float* __restrict__ bt1,
                                               const float* __restrict__ W2,
                                               const float* __restrict__ b2,
                                               const float* __restrict__ g2,
                                               const float* __restrict__ bt2,
                                               const float* __restrict__ Wk,
                                               const float* __restrict__ bk,
                                               const float* __restrict__ Wq,
                                               const float* __restrict__ Wv,
                                               const float* __restrict__ bv,
                                               float* __restrict__ w_out,
                                               float* __restrict__ g_h8) {
    __shared__ float sW1[128], sb1[16], sg1[16], sbt1[16];
    __shared__ float sW2[128], sb2[8], sg2[8], sbt2[8];
    __shared__ float sWk[64], sWv[64], sbk[8], sbv[8], sWq[8];
    __shared__ float sRed[4][4][8];
    int t = threadIdx.x;
    if (t < 128) { sW1[t] = W1[t]; sW2[t] = W2[t]; }
    if (t < 64)  { sWk[t] = Wk[t]; sWv[t] = Wv[t]; }
    if (t < 16)  { sb1[t] = b1[t]; sg1[t] = g1[t]; sbt1[t] = bt1[t]; }
    if (t < 8)   { sb2[t] = b2[t]; sg2[t] = g2[t]; sbt2[t] = bt2[t];
                   sbk[t] = bk[t]; sbv[t] = bv[t]; sWq[t] = Wq[t]; }

    int chunk = blockIdx.x & 3;
    int g = (blockIdx.x >> 2) * 16 + (t >> 4);
    int u = t & 15;
    int half = u >> 3;
    int colpos = u & 7;
    int fh = colpos & 1;
    int jgroup = half * 2 + fh;
    int b = chunk * 4 + (colpos >> 1);
    int col = chunk * 32 + colpos * 4;
    const u16* __restrict__ hc = hin + col;
    float epsv = 1.0f + eps_l[0];

    float a0, a1, a2, a3;
    if (half == 0) {
        uint2 su = *(const uint2*)(hc + (size_t)g * 128);
        a0 = bflo(su.x) * epsv; a1 = bfhi(su.x) * epsv;
        a2 = bflo(su.y) * epsv; a3 = bfhi(su.y) * epsv;
    } else {
        a0 = a1 = a2 = a3 = 0.0f;
    }

    int s = g * MAXDEG;
    int e = cursor[g];
    e = (e < s + MAXDEG) ? e : (s + MAXDEG);
    int k = s + half;
    for (; k + 14 < e; k += 16) {
        int i0 = csr_src[k],      i1 = csr_src[k + 2];
        int i2 = csr_src[k + 4],  i3 = csr_src[k + 6];
        int i4 = csr_src[k + 8],  i5 = csr_src[k + 10];
        int i6 = csr_src[k + 12], i7 = csr_src[k + 14];
        uint2 v0 = *(const uint2*)(hc + (size_t)i0 * 128);
        uint2 v1 = *(const uint2*)(hc + (size_t)i1 * 128);
        uint2 v2 = *(const uint2*)(hc + (size_t)i2 * 128);
        uint2 v3 = *(const uint2*)(hc + (size_t)i3 * 128);
        uint2 v4 = *(const uint2*)(hc + (size_t)i4 * 128);
        uint2 v5 = *(const uint2*)(hc + (size_t)i5 * 128);
        uint2 v6 = *(const uint2*)(hc + (size_t)i6 * 128);
        uint2 v7 = *(const uint2*)(hc + (size_t)i7 * 128);
        a0 += ((bflo(v0.x) + bflo(v1.x)) + (bflo(v2.x) + bflo(v3.x)))
            + ((bflo(v4.x) + bflo(v5.x)) + (bflo(v6.x) + bflo(v7.x)));
        a1 += ((bfhi(v0.x) + bfhi(v1.x)) + (bfhi(v2.x) + bfhi(v3.x)))
            + ((bfhi(v4.x) + bfhi(v5.x)) + (bfhi(v6.x) + bfhi(v7.x)));
        a2 += ((bflo(v0.y) + bflo(v1.y)) + (bflo(v2.y) + bflo(v3.y)))
            + ((bflo(v4.y) + bflo(v5.y)) + (bflo(v6.y) + bflo(v7.y)));
        a3 += ((bfhi(v0.y) + bfhi(v1.y)) + (bfhi(v2.y) + bfhi(v3.y)))
            + ((bfhi(v4.y) + bfhi(v5.y)) + (bfhi(v6.y) + bfhi(v7.y)));
    }
    for (; k < e; k += 2) {
        int i0 = csr_src[k];
        uint2 v0 = *(const uint2*)(hc + (size_t)i0 * 128);
        a0 += bflo(v0.x); a1 += bfhi(v0.x);
        a2 += bflo(v0.y); a3 += bfhi(v0.y);
    }
    __syncthreads();

    a0 += __shfl_xor(a0, 8, 64);
    a1 += __shfl_xor(a1, 8, 64);
    a2 += __shfl_xor(a2, 8, 64);
    a3 += __shfl_xor(a3, 8, 64);
    float p0 = __shfl_xor(a0, 1, 64);
    float p1 = __shfl_xor(a1, 1, 64);
    float p2 = __shfl_xor(a2, 1, 64);
    float p3 = __shfl_xor(a3, 1, 64);
    float z[8];
    z[fh * 4 + 0] = a0; z[fh * 4 + 1] = a1; z[fh * 4 + 2] = a2; z[fh * 4 + 3] = a3;
    z[(1 - fh) * 4 + 0] = p0; z[(1 - fh) * 4 + 1] = p1;
    z[(1 - fh) * 4 + 2] = p2; z[(1 - fh) * 4 + 3] = p3;

    float op[8];
    #pragma unroll
    for (int f = 0; f < 8; f++) op[f] = (jgroup == 0) ? sb2[f] : 0.0f;
    #pragma unroll
    for (int jj = 0; jj < 4; jj++) {
        int j = jgroup * 4 + jj;
        float s1 = sb1[j];
        #pragma unroll
        for (int i2 = 0; i2 < 8; i2++) s1 += z[i2] * sW1[i2 * 16 + j];
        s1 = s1 * BN_SCALE * sg1[j] + sbt1[j];
        s1 = gelu_erf(s1);
        #pragma unroll
        for (int f = 0; f < 8; f++) op[f] += s1 * sW2[j * 8 + f];
    }
    float hvh[4];
    #pragma unroll
    for (int fi = 0; fi < 4; fi++) {
        int f = fh * 4 + fi;
        float x = op[f] + __shfl_xor(op[f], 1, 64);
        x += __shfl_xor(x, 8, 64);
        hvh[fi] = gelu_erf(x * BN_SCALE * sg2[f] + sbt2[f]);
    }
    float hv[8];
    #pragma unroll
    for (int fi = 0; fi < 4; fi++) {
        hv[fh * 4 + fi] = hvh[fi];
        hv[(1 - fh) * 4 + fi] = __shfl_xor(hvh[fi], 1, 64);
    }

    float qp = 0.0f;
    #pragma unroll
    for (int jj = 0; jj < 2; jj++) {
        int j = jgroup * 2 + jj;
        float key = sbk[j];
        #pragma unroll
        for (int i2 = 0; i2 < 8; i2++) key += hv[i2] * sWk[i2 * 8 + j];
        qp += key * sWq[j];
    }
    float q = qp + __shfl_xor(qp, 1, 64);
    q += __shfl_xor(q, 8, 64);
    float w = sigmoidf_(q);
    if (fh == 0 && half == 0) w_out[(size_t)b * NGENES + g] = w;

    float contrib[4];
    #pragma unroll
    for (int fi = 0; fi < 4; fi++) {
        int f = fh * 4 + fi;
        float v = sbv[f];
        #pragma unroll
        for (int i2 = 0; i2 < 8; i2++) v += hv[i2] * sWv[i2 * 8 + f];
        contrib[fi] = (half == 0) ? v * w : 0.0f;
    }
    #pragma unroll
    for (int fi = 0; fi < 4; fi++) {
        contrib[fi] += __shfl_xor(contrib[fi], 8, 64);
        contrib[fi] += __shfl_xor(contrib[fi], 16, 64);
        contrib[fi] += __shfl_xor(contrib[fi], 32, 64);
    }
    int wave = t >> 6, lane = t & 63;
    if (lane < 8) {
        #pragma unroll
        for (int fi = 0; fi < 4; fi++)
            sRed[wave][lane >> 1][(lane & 1) * 4 + fi] = contrib[fi];
    }
    __syncthreads();
    if (t < 32) {
        int bl = t >> 3, f = t & 7;
        float sm = sRed[0][bl][f] + sRed[1][bl][f] + sRed[2][bl][f] + sRed[3][bl][f];
        int shard = (blockIdx.x >> 2) & 7;
        atomicAdd(&g_h8[shard * 128 + (chunk * 4 + bl) * 8 + f], sm);
    }
}

// ---------------------------------------------------------------------------
// kE: head MLP only (sums 8 g_h shards; thread-mapping identical to k_head).
__global__ __launch_bounds__(1024) void kE_head(const float* __restrict__ g_h8,
                                                const float* __restrict__ Wp1, const float* __restrict__ bp1,
                                                const float* __restrict__ gp1, const float* __restrict__ btp1,
                                                const float* __restrict__ Wp2, const float* __restrict__ bp2,
                                                const float* __restrict__ gp2, const float* __restrict__ btp2,
                                                const float* __restrict__ Wp3, const float* __restrict__ bp3,
                                                float* __restrict__ preds) {
    __shared__ float sgh[128];
    __shared__ float z1[16 * 64];
    __shared__ float z2[16 * 16];
    int t = threadIdx.x;
    if (t < 128) {
        float s01 = g_h8[t]           + g_h8[128 + t];
        float s23 = g_h8[256 + t]     + g_h8[384 + t];
        float s45 = g_h8[512 + t]     + g_h8[640 + t];
        float s67 = g_h8[768 + t]     + g_h8[896 + t];
        sgh[t] = (s01 + s23) + (s45 + s67);
    }
    __syncthreads();
    {
        int b = t >> 6, j = t & 63;
        float s = bp1[j];
        #pragma unroll
        for (int k = 0; k < 8; k++) s += sgh[b * 8 + k] * Wp1[k * 64 + j];
        s = s * BN_SCALE * gp1[j] + btp1[j];
        z1[b * 64 + j] = gelu_erf(s);
    }
    __syncthreads();
    if (t < 256) {
        int b = t >> 4, j = t & 15;
        float s = bp2[j];
        for (int k = 0; k < 64; k++) s += z1[b * 64 + k] * Wp2[k * 16 + j];
        s = s * BN_SCALE * gp2[j] + btp2[j];
        z2[b * 16 + j] = gelu_erf(s);
    }
    __syncthreads();
    if (t < 16) {
        float s = bp3[0];
        #pragma unroll
        for (int k = 0; k < 16; k++) s += z2[t * 16 + k] * Wp3[k];
        preds[t] = s;
    }
}

// ---------------------------------------------------------------------------
extern "C" void kernel_launch(void* const* d_in, const int* in_sizes, int n_in,
                              void* d_out, int out_size, void* d_ws, size_t ws_size,
                              hipStream_t stream) {
    const float* snp          = (const float*)d_in[0];
    const int*   snp_ids      = (const int*)  d_in[1];
    const int*   gene_of_node = (const int*)  d_in[2];
    const int*   edge_src     = (const int*)  d_in[3];
    const int*   edge_dst     = (const int*)  d_in[4];
    const float* filters      = (const float*)d_in[5];
    const float* eps          = (const float*)d_in[6];
    const float* W1  = (const float*)d_in[7];
    const float* b1  = (const float*)d_in[8];
    const float* g1  = (const float*)d_in[9];
    const float* bt1 = (const float*)d_in[10];
    const float* W2  = (const float*)d_in[11];
    const float* b2  = (const float*)d_in[12];
    const float* g2  = (const float*)d_in[13];
    const float* bt2 = (const float*)d_in[14];
    const float* Wk  = (const float*)d_in[15];
    const float* bk  = (const float*)d_in[16];
    const float* Wq  = (const float*)d_in[17];
    const float* Wv  = (const float*)d_in[18];
    const float* bv  = (const float*)d_in[19];
    const float* Wp1 = (const float*)d_in[20];
    const float* bp1 = (const float*)d_in[21];
    const float* gp1 = (const float*)d_in[22];
    const float* btp1= (const float*)d_in[23];
    const float* Wp2 = (const float*)d_in[24];
    const float* bp2 = (const float*)d_in[25];
    const float* gp2 = (const float*)d_in[26];
    const float* btp2= (const float*)d_in[27];
    const float* Wp3 = (const float*)d_in[28];
    const float* bp3 = (const float*)d_in[29];

    float* out        = (float*)d_out;
    float* out_preds  = out;
    float* out_filt   = out + 16;
    float* out_w      = out + 16 + NFILT * NSNPS;

    // ---- workspace layout
    char* ws = (char*)d_ws;
    size_t off = 0;
    u16* nodeRow = (u16*)(ws + off); off += (size_t)NSNPS * 64;                  // 32 MB
    u16* h0   = (u16*)(ws + off); off += (size_t)NGENES * 128 * 2;               // 5.12 MB
    u16* h1   = (u16*)(ws + off); off += (size_t)NGENES * 128 * 2;               // 5.12 MB
    int* node_off = (int*)(ws + off); off += ((NGENES + 1) * 4 + 255) / 256 * 256;
    int* cursor   = (int*)(ws + off); off += (NGENES * 4 + 255) / 256 * 256;
    int* csr_src  = (int*)(ws + off); off += (size_t)NGENES * MAXDEG * 4;        // 5.12 MB
    float* g_h8   = (float*)(ws + off); off += 8 * 128 * 4;

    // 1. prep: node rows + out_filt + node_off + cursor init + g_h8 zero (no LDS)
    kA_prep<<<KA_NA + KA_NB, 256, 0, stream>>>(
        snp, filters, gene_of_node, nodeRow, out_filt, node_off, cursor, g_h8);
    // 2. scatter (first — no tail) + barrier-free per-wave gather
    kB_gather<<<KB_SCAT + KB_GATH, 256, 0, stream>>>(
        nodeRow, snp_ids, node_off, edge_src, edge_dst, cursor, csr_src, h0);
    // 3. GIN layer 1
    kC_gin1<<<NBLK2, 256, 0, stream>>>(h0, h1, cursor, csr_src, eps + 0,
                                       W1 + 0 * 128, b1 + 0 * 16, g1 + 0 * 16, bt1 + 0 * 16,
                                       W2 + 0 * 128, b2 + 0 * 8, g2 + 0 * 8, bt2 + 0 * 8);
    // 4. GIN layer 2 + readout (8-sharded atomic g_h8)
    kD_gin2<<<NBLK2, 256, 0, stream>>>(h1, cursor, csr_src, eps + 1,
                                       W1 + 1 * 128, b1 + 1 * 16, g1 + 1 * 16, bt1 + 1 * 16,
                                       W2 + 1 * 128, b2 + 1 * 8, g2 + 1 * 8, bt2 + 1 * 8,
                                       Wk, bk, Wq, Wv, bv, out_w, g_h8);
    // 5. head MLP
    kE_head<<<1, 1024, 0, stream>>>(g_h8, Wp1, bp1, gp1, btp1,
                                    Wp2, bp2, gp2, btp2, Wp3, bp3, out_preds);
}